// Round 14
// baseline (440.040 us; speedup 1.0000x reference)
//
#include <hip/hip_runtime.h>
#include <hip/hip_bf16.h>

#define N_NODES 100000
#define N_EDGES 1600000
#define NBUCK 256
#define NODES_PER_BUCKET 391        // 256*391 = 100096 >= 100000
#define EDGES_PER_CHUNK (N_EDGES / NBUCK)   // 6250 exactly
#define FILL_LDS_CAP 8192           // mean 6250, sigma~79 -> +24 sigma

typedef __bf16 bf16x8 __attribute__((ext_vector_type(8)));
typedef float f32x4 __attribute__((ext_vector_type(4)));

// ---------------- helpers ----------------

__device__ inline unsigned short f2bf_rne(float v) {
    unsigned u = __float_as_uint(v);
    u += 0x7fffu + ((u >> 16) & 1u);
    return (unsigned short)(u >> 16);
}

__device__ inline unsigned pack_bf(float a, float b) {
    return (unsigned)f2bf_rne(a) | ((unsigned)f2bf_rne(b) << 16);
}

__device__ inline void acc8_bf(float* a, uint4 p) {
    a[0] += __uint_as_float(p.x << 16);
    a[1] += __uint_as_float(p.x & 0xffff0000u);
    a[2] += __uint_as_float(p.y << 16);
    a[3] += __uint_as_float(p.y & 0xffff0000u);
    a[4] += __uint_as_float(p.z << 16);
    a[5] += __uint_as_float(p.z & 0xffff0000u);
    a[6] += __uint_as_float(p.w << 16);
    a[7] += __uint_as_float(p.w & 0xffff0000u);
}

// ---------------- CSR build: 256-bucket counting sort, coalesced writes ----

__global__ __launch_bounds__(256) void pa_count(const int* __restrict__ dst,
                                                int* __restrict__ blkCntT) {
    __shared__ int hist[NBUCK];
    hist[threadIdx.x] = 0;
    __syncthreads();
    int b0 = blockIdx.x * EDGES_PER_CHUNK;
    int b1 = min(b0 + EDGES_PER_CHUNK, N_EDGES);
    for (int i = b0 + (int)threadIdx.x; i < b1; i += 256) {
        int d = __builtin_nontemporal_load(&dst[i]);
        atomicAdd(&hist[d / NODES_PER_BUCKET], 1);
    }
    __syncthreads();
    blkCntT[threadIdx.x * NBUCK + blockIdx.x] = hist[threadIdx.x];
}

__global__ __launch_bounds__(256) void pa_scan1(const int* __restrict__ blkCntT,
                                                int* __restrict__ blkBaseL,
                                                int* __restrict__ bucketTotal) {
    __shared__ int s[256];
    int t = threadIdx.x;
    int v = blkCntT[blockIdx.x * NBUCK + t];
    s[t] = v;
    __syncthreads();
    for (int off = 1; off < 256; off <<= 1) {
        int u = (t >= off) ? s[t - off] : 0;
        __syncthreads();
        s[t] += u;
        __syncthreads();
    }
    blkBaseL[blockIdx.x * NBUCK + t] = s[t] - v;
    if (t == 255) bucketTotal[blockIdx.x] = s[255];
}

__global__ __launch_bounds__(256) void pa_scan2(const int* __restrict__ bucketTotal,
                                                int* __restrict__ bstart,
                                                int* __restrict__ offsets) {
    __shared__ int s[256];
    int t = threadIdx.x;
    int v = bucketTotal[t];
    s[t] = v;
    __syncthreads();
    for (int off = 1; off < 256; off <<= 1) {
        int u = (t >= off) ? s[t - off] : 0;
        __syncthreads();
        s[t] += u;
        __syncthreads();
    }
    bstart[t] = s[t] - v;
    if (t == 255) {
        bstart[256] = s[255];
        offsets[N_NODES] = s[255];
    }
}

__global__ __launch_bounds__(256) void pa_scatter(const int* __restrict__ src,
                                                  const int* __restrict__ dst,
                                                  const int* __restrict__ blkBaseL,
                                                  const int* __restrict__ bstart,
                                                  int2* __restrict__ staging) {
    __shared__ int hist[NBUCK];
    __shared__ int runStart[NBUCK];
    __shared__ int cur[NBUCK];
    __shared__ int gbase[NBUCK];
    __shared__ int2 buf[EDGES_PER_CHUNK];

    const int tid = threadIdx.x;
    const int g = blockIdx.x;
    const int b0 = g * EDGES_PER_CHUNK;
    const int b1 = min(b0 + EDGES_PER_CHUNK, N_EDGES);

    hist[tid] = 0;
    __syncthreads();
    for (int i = b0 + tid; i < b1; i += 256) {
        int d = __builtin_nontemporal_load(&dst[i]);
        atomicAdd(&hist[d / NODES_PER_BUCKET], 1);
    }
    __syncthreads();
    {
        __shared__ int s[256];
        int v = hist[tid];
        s[tid] = v;
        __syncthreads();
        for (int off = 1; off < 256; off <<= 1) {
            int u = (tid >= off) ? s[tid - off] : 0;
            __syncthreads();
            s[tid] += u;
            __syncthreads();
        }
        runStart[tid] = s[tid] - v;
        cur[tid] = s[tid] - v;
        gbase[tid] = bstart[tid] + blkBaseL[tid * NBUCK + g];
    }
    __syncthreads();
    for (int i = b0 + tid; i < b1; i += 256) {
        int d = __builtin_nontemporal_load(&dst[i]);
        int s_ = __builtin_nontemporal_load(&src[i]);
        int k = d / NODES_PER_BUCKET;
        int p = atomicAdd(&cur[k], 1);
        buf[p] = make_int2(s_, d);
    }
    __syncthreads();
    int cnt = b1 - b0;
    for (int i = tid; i < cnt; i += 256) {
        int2 e = buf[i];
        int k = e.y / NODES_PER_BUCKET;
        staging[gbase[k] + (i - runStart[k])] = e;
    }
}

__global__ __launch_bounds__(512) void pc_fill(const int2* __restrict__ staging,
                                               const int* __restrict__ bstart,
                                               int* __restrict__ ssrc,
                                               int* __restrict__ offsets,
                                               float* __restrict__ inv_deg) {
    __shared__ int scnt[NODES_PER_BUCKET];
    __shared__ int sexc[NODES_PER_BUCKET];
    __shared__ int scur[NODES_PER_BUCKET];
    __shared__ int ssrcL[FILL_LDS_CAP];

    const int tid = threadIdx.x;
    const int b = blockIdx.x;
    const int node0 = b * NODES_PER_BUCKET;
    const int nn = min(node0 + NODES_PER_BUCKET, N_NODES) - node0;
    if (nn <= 0) return;
    const int es = bstart[b], ee = bstart[b + 1];
    const int cnt = ee - es;

    for (int j = tid; j < nn; j += 512) scnt[j] = 0;
    __syncthreads();
    for (int i = es + tid; i < ee; i += 512) {
        int2 e = staging[i];
        atomicAdd(&scnt[e.y - node0], 1);
    }
    __syncthreads();

    if (tid < 64) {
        int base = tid * 7;
        int vals[7];
        int run = 0;
#pragma unroll
        for (int j = 0; j < 7; ++j) {
            int idx = base + j;
            int c = (idx < nn) ? scnt[idx] : 0;
            vals[j] = run;
            run += c;
        }
        int inc = run;
#pragma unroll
        for (int off = 1; off < 64; off <<= 1) {
            int u = __shfl_up(inc, off, 64);
            if (tid >= off) inc += u;
        }
        int laneExcl = inc - run;
#pragma unroll
        for (int j = 0; j < 7; ++j) {
            int idx = base + j;
            if (idx < nn) sexc[idx] = laneExcl + vals[j];
        }
    }
    __syncthreads();

    for (int j = tid; j < nn; j += 512) {
        int c = scnt[j];
        int ex = sexc[j];
        offsets[node0 + j] = es + ex;
        inv_deg[node0 + j] = 1.0f / (float)max(c, 1);
        scur[j] = ex;
    }
    __syncthreads();

    if (cnt <= FILL_LDS_CAP) {
        for (int i = es + tid; i < ee; i += 512) {
            int2 e = staging[i];
            int p = atomicAdd(&scur[e.y - node0], 1);
            ssrcL[p] = e.x;
        }
        __syncthreads();
        for (int i = tid; i < cnt; i += 512) ssrc[es + i] = ssrcL[i];
    } else {
        for (int i = es + tid; i < ee; i += 512) {
            int2 e = staging[i];
            int p = atomicAdd(&scur[e.y - node0], 1);
            ssrc[es + p] = e.x;
        }
    }
}

// ---------------- aggregation ----------------

// Feature-sliced 128-wide gather (R13 post-mortem): h1/aggB stored as 8
// planes of 32 B/node (plane = 3.2 MB, fits one XCD 4 MB L2). slice =
// blockIdx&7 matches round-robin block->XCD -> plane stays L2-resident.
// 2 threads/node; indices re-read per slice (streamed, cheap vs random).
__global__ __launch_bounds__(256) void aggregate_bf128s(const unsigned short* __restrict__ hb,
                                                        const int* __restrict__ offs,
                                                        const int* __restrict__ ssrc,
                                                        const float* __restrict__ inv_deg,
                                                        unsigned short* __restrict__ aggb,
                                                        int nnodes) {
    const int s = blockIdx.x & 7;
    const int node = (blockIdx.x >> 3) * 128 + ((int)threadIdx.x >> 1);
    const int half = threadIdx.x & 1;
    if (node >= nnodes) return;
    const uint4* __restrict__ hp = (const uint4*)hb + (size_t)s * nnodes * 2;
    int b = offs[node], e = offs[node + 1];
    float acc[8] = {0.f, 0.f, 0.f, 0.f, 0.f, 0.f, 0.f, 0.f};
    int i = b;
    for (; i + 4 <= e; i += 4) {
        uint4 p0 = hp[(size_t)ssrc[i] * 2 + half];
        uint4 p1 = hp[(size_t)ssrc[i + 1] * 2 + half];
        uint4 p2 = hp[(size_t)ssrc[i + 2] * 2 + half];
        uint4 p3 = hp[(size_t)ssrc[i + 3] * 2 + half];
        acc8_bf(acc, p0);
        acc8_bf(acc, p1);
        acc8_bf(acc, p2);
        acc8_bf(acc, p3);
    }
    for (; i < e; ++i) acc8_bf(acc, hp[(size_t)ssrc[i] * 2 + half]);
    float sc = inv_deg[node];
    uint4 o;
    o.x = pack_bf(acc[0] * sc, acc[1] * sc);
    o.y = pack_bf(acc[2] * sc, acc[3] * sc);
    o.z = pack_bf(acc[4] * sc, acc[5] * sc);
    o.w = pack_bf(acc[6] * sc, acc[7] * sc);
    ((uint4*)aggb)[(size_t)s * nnodes * 2 + (size_t)node * 2 + half] = o;
}

__global__ __launch_bounds__(256) void aggregate_bf32(const unsigned short* __restrict__ hb,
                                                      const int* __restrict__ offs,
                                                      const int* __restrict__ ssrc,
                                                      const float* __restrict__ inv_deg,
                                                      float* __restrict__ agg, int nnodes) {
    int t = blockIdx.x * 256 + threadIdx.x;
    if (t >= nnodes * 4) return;
    int node = t >> 2;
    int c = t & 3;
    int b = offs[node], e = offs[node + 1];
    const uint4* __restrict__ hb4 = (const uint4*)hb;
    float acc[8] = {0.f, 0.f, 0.f, 0.f, 0.f, 0.f, 0.f, 0.f};
    int i = b;
    for (; i + 4 <= e; i += 4) {
        uint4 p0 = hb4[(size_t)ssrc[i] * 4 + c];
        uint4 p1 = hb4[(size_t)ssrc[i + 1] * 4 + c];
        uint4 p2 = hb4[(size_t)ssrc[i + 2] * 4 + c];
        uint4 p3 = hb4[(size_t)ssrc[i + 3] * 4 + c];
        acc8_bf(acc, p0);
        acc8_bf(acc, p1);
        acc8_bf(acc, p2);
        acc8_bf(acc, p3);
    }
    for (; i < e; ++i) {
        uint4 p = hb4[(size_t)ssrc[i] * 4 + c];
        acc8_bf(acc, p);
    }
    float s = inv_deg[node];
    float4* outp = (float4*)&agg[(size_t)node * 32 + c * 8];
    outp[0] = make_float4(acc[0] * s, acc[1] * s, acc[2] * s, acc[3] * s);
    outp[1] = make_float4(acc[4] * s, acc[5] * s, acc[6] * s, acc[7] * s);
}

__global__ __launch_bounds__(256) void aggregate2(const float* __restrict__ h,
                                                  const int* __restrict__ offs,
                                                  const int* __restrict__ ssrc,
                                                  const float* __restrict__ inv_deg,
                                                  float* __restrict__ agg, int nnodes) {
    int node = blockIdx.x * blockDim.x + threadIdx.x;
    if (node >= nnodes) return;
    int b = offs[node], e = offs[node + 1];
    const float2* __restrict__ h2 = (const float2*)h;
    float2 a0 = make_float2(0.f, 0.f), a1 = make_float2(0.f, 0.f);
    int i = b;
    for (; i + 2 <= e; i += 2) {
        float2 v = h2[ssrc[i]];
        float2 w = h2[ssrc[i + 1]];
        a0.x += v.x; a0.y += v.y;
        a1.x += w.x; a1.y += w.y;
    }
    if (i < e) {
        float2 v = h2[ssrc[i]];
        a0.x += v.x; a0.y += v.y;
    }
    float s = inv_deg[node];
    ((float2*)agg)[node] = make_float2((a0.x + a1.x) * s, (a0.y + a1.y) * s);
}

// ---------------- layer-2 weight prep ----------------

__global__ __launch_bounds__(256) void prep_wt(const float* __restrict__ Wl,
                                               const float* __restrict__ Wr,
                                               unsigned short* __restrict__ Wt) {
    int idx = blockIdx.x * 256 + threadIdx.x;
    int n = idx >> 8;
    int k = idx & 255;
    float v = (k < 128) ? Wl[k * 128 + n] : Wr[(k - 128) * 128 + n];
    Wt[idx] = f2bf_rne(v);
}

// ---------------- layer-2 MFMA GEMM (A operands in sliced layout) ----------

__global__ __launch_bounds__(256) void gemm_l2_mfma(const unsigned short* __restrict__ Ab,
                                                    const unsigned short* __restrict__ Hb,
                                                    const unsigned short* __restrict__ Wt,
                                                    const float* __restrict__ bias,
                                                    float* __restrict__ C, int M) {
    constexpr int BM = 128, BK = 64;
    __shared__ unsigned short sA[BM][BK + 8];
    __shared__ unsigned short sB[128][BK + 8];

    const int tid = threadIdx.x;
    const int m0 = blockIdx.x * BM;
    const int lane = tid & 63;
    const int wid = tid >> 6;
    const int l15 = lane & 15;
    const int quad = lane >> 4;
    const int wm = (wid >> 1) * 64;
    const int wn = (wid & 1) * 64;

    f32x4 acc[4][4];
#pragma unroll
    for (int i = 0; i < 4; ++i)
#pragma unroll
        for (int j = 0; j < 4; ++j) acc[i][j] = (f32x4){0.f, 0.f, 0.f, 0.f};

    for (int k0 = 0; k0 < 256; k0 += BK) {
        const uint4* __restrict__ srcA = (const uint4*)((k0 < 128) ? Ab : Hb);
        const int kcChunk = (k0 & 64) >> 3;   // uint4-chunk base within the 128-k half
#pragma unroll
        for (int l = 0; l < 4; ++l) {
            int idx = tid + l * 256;
            int row = idx >> 3;
            int c8 = idx & 7;
            int gr = min(m0 + row, M - 1);
            int chunk = kcChunk + c8;         // 0..15 over k'=0..127
            // sliced: plane = chunk>>1 (16 feats), uint4 col within plane = chunk&1
            uint4 va = srcA[(size_t)(chunk >> 1) * N_NODES * 2 + (size_t)gr * 2 + (chunk & 1)];
            *(uint4*)&sA[row][c8 * 8] = va;
            uint4 vb = ((const uint4*)Wt)[(size_t)row * 32 + (k0 >> 3) + c8];
            *(uint4*)&sB[row][c8 * 8] = vb;
        }
        __syncthreads();

#pragma unroll
        for (int ks = 0; ks < BK; ks += 32) {
            bf16x8 a[4], b[4];
#pragma unroll
            for (int t = 0; t < 4; ++t) {
                a[t] = *(const bf16x8*)&sA[wm + t * 16 + l15][ks + quad * 8];
                b[t] = *(const bf16x8*)&sB[wn + t * 16 + l15][ks + quad * 8];
            }
#pragma unroll
            for (int i = 0; i < 4; ++i)
#pragma unroll
                for (int j = 0; j < 4; ++j)
                    acc[i][j] = __builtin_amdgcn_mfma_f32_16x16x32_bf16(
                        a[i], b[j], acc[i][j], 0, 0, 0);
        }
        __syncthreads();
    }

#pragma unroll
    for (int j = 0; j < 4; ++j) {
        int n = wn + j * 16 + l15;
        float bv = bias[n];
#pragma unroll
        for (int i = 0; i < 4; ++i) {
#pragma unroll
            for (int r = 0; r < 4; ++r) {
                int m = m0 + wm + i * 16 + quad * 4 + r;
                if (m < M) C[(size_t)m * 128 + n] = fmaxf(acc[i][j][r] + bv, 0.f);
            }
        }
    }
}

// ---------------- Cout=32 GEMMs ----------------

template <int Cin, bool EMIT_BF, bool FUSE_OUT>
__global__ __launch_bounds__(256) void gemm_n32(const float* __restrict__ A0,
                                                const float* __restrict__ A1,
                                                const float* __restrict__ W0,
                                                const float* __restrict__ bias,
                                                const float* __restrict__ W1,
                                                float* __restrict__ C,
                                                unsigned short* __restrict__ Cbf,
                                                const float* __restrict__ Wout,
                                                const float* __restrict__ bout,
                                                float* __restrict__ out, int M) {
    constexpr int COUT = 32, BM = 128, BK = 16;
    __shared__ float sA0[BK][BM + 4];
    __shared__ float sA1[BK][BM + 4];
    __shared__ float sW0[BK][36];
    __shared__ float sW1[BK][36];

    const int tid = threadIdx.x;
    const int m0 = blockIdx.x * BM;
    const int tr = tid >> 3;
    const int tc = tid & 7;

    float acc[4][4];
#pragma unroll
    for (int i = 0; i < 4; ++i)
#pragma unroll
        for (int j = 0; j < 4; ++j) acc[i][j] = 0.f;

    const int wrow = tid >> 3;
    const int wc4  = tid & 7;

    for (int k0 = 0; k0 < Cin; k0 += BK) {
#pragma unroll
        for (int l = 0; l < 2; ++l) {
            int idx = tid + l * 256;
            int row = idx >> 2;
            int c4  = idx & 3;
            int gr  = min(m0 + row, M - 1);
            float4 v0 = *(const float4*)&A0[(size_t)gr * Cin + k0 + c4 * 4];
            float4 v1 = *(const float4*)&A1[(size_t)gr * Cin + k0 + c4 * 4];
            sA0[c4 * 4 + 0][row] = v0.x; sA0[c4 * 4 + 1][row] = v0.y;
            sA0[c4 * 4 + 2][row] = v0.z; sA0[c4 * 4 + 3][row] = v0.w;
            sA1[c4 * 4 + 0][row] = v1.x; sA1[c4 * 4 + 1][row] = v1.y;
            sA1[c4 * 4 + 2][row] = v1.z; sA1[c4 * 4 + 3][row] = v1.w;
        }
        if (tid < 128) {
            float4 w0 = *(const float4*)&W0[(size_t)(k0 + wrow) * COUT + wc4 * 4];
            float4 w1 = *(const float4*)&W1[(size_t)(k0 + wrow) * COUT + wc4 * 4];
            *(float4*)&sW0[wrow][wc4 * 4] = w0;
            *(float4*)&sW1[wrow][wc4 * 4] = w1;
        }
        __syncthreads();

#pragma unroll
        for (int k = 0; k < BK; ++k) {
            float4 a0 = *(const float4*)&sA0[k][tr * 4];
            float4 a1 = *(const float4*)&sA1[k][tr * 4];
            float4 w0 = *(const float4*)&sW0[k][tc * 4];
            float4 w1 = *(const float4*)&sW1[k][tc * 4];
            float av0[4] = {a0.x, a0.y, a0.z, a0.w};
            float av1[4] = {a1.x, a1.y, a1.z, a1.w};
            float wv0[4] = {w0.x, w0.y, w0.z, w0.w};
            float wv1[4] = {w1.x, w1.y, w1.z, w1.w};
#pragma unroll
            for (int i = 0; i < 4; ++i)
#pragma unroll
                for (int j = 0; j < 4; ++j)
                    acc[i][j] = fmaf(av0[i], wv0[j], fmaf(av1[i], wv1[j], acc[i][j]));
        }
        __syncthreads();
    }

#pragma unroll
    for (int i = 0; i < 4; ++i) {
        int m = m0 + tr * 4 + i;
        if (m >= M) continue;
        int n = tc * 4;
        float4 bv = *(const float4*)&bias[n];
        float4 r;
        r.x = fmaxf(acc[i][0] + bv.x, 0.f);
        r.y = fmaxf(acc[i][1] + bv.y, 0.f);
        r.z = fmaxf(acc[i][2] + bv.z, 0.f);
        r.w = fmaxf(acc[i][3] + bv.w, 0.f);
        if (FUSE_OUT) {
            float p = r.x * Wout[n] + r.y * Wout[n + 1] +
                      r.z * Wout[n + 2] + r.w * Wout[n + 3];
            p += __shfl_down(p, 4, 8);
            p += __shfl_down(p, 2, 8);
            p += __shfl_down(p, 1, 8);
            if (tc == 0) out[m] = p + bout[0];
        } else {
            *(float4*)&C[(size_t)m * COUT + n] = r;
            if (EMIT_BF) {
                uint2 o;
                o.x = pack_bf(r.x, r.y);
                o.y = pack_bf(r.z, r.w);
                *(uint2*)&Cbf[(size_t)m * COUT + n] = o;
            }
        }
    }
}

template <int Cin>
__global__ __launch_bounds__(256) void gemm_pre32(const float* __restrict__ A,
                                                  const float* __restrict__ W,
                                                  unsigned short* __restrict__ Cbf, int M) {
    constexpr int COUT = 32, BM = 128, BK = 16;
    __shared__ float sA[BK][BM + 4];
    __shared__ float sW[BK][36];

    const int tid = threadIdx.x;
    const int m0 = blockIdx.x * BM;
    const int tr = tid >> 3;
    const int tc = tid & 7;

    float acc[4][4];
#pragma unroll
    for (int i = 0; i < 4; ++i)
#pragma unroll
        for (int j = 0; j < 4; ++j) acc[i][j] = 0.f;

    const int wrow = tid >> 3;
    const int wc4  = tid & 7;

    for (int k0 = 0; k0 < Cin; k0 += BK) {
#pragma unroll
        for (int l = 0; l < 2; ++l) {
            int idx = tid + l * 256;
            int row = idx >> 2;
            int c4  = idx & 3;
            int gr  = min(m0 + row, M - 1);
            float4 v = *(const float4*)&A[(size_t)gr * Cin + k0 + c4 * 4];
            sA[c4 * 4 + 0][row] = v.x; sA[c4 * 4 + 1][row] = v.y;
            sA[c4 * 4 + 2][row] = v.z; sA[c4 * 4 + 3][row] = v.w;
        }
        if (tid < 128) {
            float4 w = *(const float4*)&W[(size_t)(k0 + wrow) * COUT + wc4 * 4];
            *(float4*)&sW[wrow][wc4 * 4] = w;
        }
        __syncthreads();

#pragma unroll
        for (int k = 0; k < BK; ++k) {
            float4 a = *(const float4*)&sA[k][tr * 4];
            float4 w = *(const float4*)&sW[k][tc * 4];
            float av[4] = {a.x, a.y, a.z, a.w};
            float wv[4] = {w.x, w.y, w.z, w.w};
#pragma unroll
            for (int i = 0; i < 4; ++i)
#pragma unroll
                for (int j = 0; j < 4; ++j)
                    acc[i][j] = fmaf(av[i], wv[j], acc[i][j]);
        }
        __syncthreads();
    }

#pragma unroll
    for (int i = 0; i < 4; ++i) {
        int m = m0 + tr * 4 + i;
        if (m >= M) continue;
        int n = tc * 4;
        uint2 o;
        o.x = pack_bf(acc[i][0], acc[i][1]);
        o.y = pack_bf(acc[i][2], acc[i][3]);
        *(uint2*)&Cbf[(size_t)m * COUT + n] = o;
    }
}

template <int Cin>
__global__ __launch_bounds__(256) void gemm_post32(const float* __restrict__ agg,
                                                   const float* __restrict__ A,
                                                   const float* __restrict__ W,
                                                   const float* __restrict__ bias,
                                                   float* __restrict__ C,
                                                   unsigned short* __restrict__ Cbf, int M) {
    constexpr int COUT = 32, BM = 128, BK = 16;
    __shared__ float sA[BK][BM + 4];
    __shared__ float sW[BK][36];

    const int tid = threadIdx.x;
    const int m0 = blockIdx.x * BM;
    const int tr = tid >> 3;
    const int tc = tid & 7;

    float acc[4][4];
#pragma unroll
    for (int i = 0; i < 4; ++i)
#pragma unroll
        for (int j = 0; j < 4; ++j) acc[i][j] = 0.f;

    const int wrow = tid >> 3;
    const int wc4  = tid & 7;

    for (int k0 = 0; k0 < Cin; k0 += BK) {
#pragma unroll
        for (int l = 0; l < 2; ++l) {
            int idx = tid + l * 256;
            int row = idx >> 2;
            int c4  = idx & 3;
            int gr  = min(m0 + row, M - 1);
            float4 v = *(const float4*)&A[(size_t)gr * Cin + k0 + c4 * 4];
            sA[c4 * 4 + 0][row] = v.x; sA[c4 * 4 + 1][row] = v.y;
            sA[c4 * 4 + 2][row] = v.z; sA[c4 * 4 + 3][row] = v.w;
        }
        if (tid < 128) {
            float4 w = *(const float4*)&W[(size_t)(k0 + wrow) * COUT + wc4 * 4];
            *(float4*)&sW[wrow][wc4 * 4] = w;
        }
        __syncthreads();

#pragma unroll
        for (int k = 0; k < BK; ++k) {
            float4 a = *(const float4*)&sA[k][tr * 4];
            float4 w = *(const float4*)&sW[k][tc * 4];
            float av[4] = {a.x, a.y, a.z, a.w};
            float wv[4] = {w.x, w.y, w.z, w.w};
#pragma unroll
            for (int i = 0; i < 4; ++i)
#pragma unroll
                for (int j = 0; j < 4; ++j)
                    acc[i][j] = fmaf(av[i], wv[j], acc[i][j]);
        }
        __syncthreads();
    }

#pragma unroll
    for (int i = 0; i < 4; ++i) {
        int m = m0 + tr * 4 + i;
        if (m >= M) continue;
        int n = tc * 4;
        float4 bv = *(const float4*)&bias[n];
        float4 gv = *(const float4*)&agg[(size_t)m * COUT + n];
        float4 r;
        r.x = fmaxf(acc[i][0] + gv.x + bv.x, 0.f);
        r.y = fmaxf(acc[i][1] + gv.y + bv.y, 0.f);
        r.z = fmaxf(acc[i][2] + gv.z + bv.z, 0.f);
        r.w = fmaxf(acc[i][3] + gv.w + bv.w, 0.f);
        *(float4*)&C[(size_t)m * COUT + n] = r;
        uint2 o;
        o.x = pack_bf(r.x, r.y);
        o.y = pack_bf(r.z, r.w);
        *(uint2*)&Cbf[(size_t)m * COUT + n] = o;
    }
}

// layer-1 linear (Cin=2): bf16 output in SLICED layout (plane = c>>4)
__global__ __launch_bounds__(256) void sage_linear2(const float* __restrict__ agg,
                                                    const float* __restrict__ h,
                                                    const float* __restrict__ Wl,
                                                    const float* __restrict__ bl,
                                                    const float* __restrict__ Wr,
                                                    unsigned short* __restrict__ out_bf,
                                                    int nnodes) {
    constexpr int Cout = 128;
    int t = blockIdx.x * blockDim.x + threadIdx.x;
    if (t >= nnodes * Cout) return;
    int node = t / Cout;
    int c = t - node * Cout;
    float2 a = ((const float2*)agg)[node];
    float2 hh = ((const float2*)h)[node];
    float acc = bl[c];
    acc = fmaf(a.x, Wl[c], acc);
    acc = fmaf(a.y, Wl[Cout + c], acc);
    acc = fmaf(hh.x, Wr[c], acc);
    acc = fmaf(hh.y, Wr[Cout + c], acc);
    acc = fmaxf(acc, 0.f);
    out_bf[(size_t)(c >> 4) * nnodes * 16 + (size_t)node * 16 + (c & 15)] = f2bf_rne(acc);
}

// ---------------- launch ----------------

extern "C" void kernel_launch(void* const* d_in, const int* in_sizes, int n_in,
                              void* d_out, int out_size, void* d_ws, size_t ws_size,
                              hipStream_t stream) {
    const float* x      = (const float*)d_in[0];
    const int*   ei     = (const int*)d_in[1];
    const float* Wl1    = (const float*)d_in[3];
    const float* bl1    = (const float*)d_in[4];
    const float* Wr1    = (const float*)d_in[5];
    const float* Wl2    = (const float*)d_in[6];
    const float* bl2    = (const float*)d_in[7];
    const float* Wr2    = (const float*)d_in[8];
    const float* Wl3    = (const float*)d_in[9];
    const float* bl3    = (const float*)d_in[10];
    const float* Wr3    = (const float*)d_in[11];
    const float* Wl4    = (const float*)d_in[12];
    const float* bl4    = (const float*)d_in[13];
    const float* Wr4    = (const float*)d_in[14];
    const float* Wl5    = (const float*)d_in[15];
    const float* bl5    = (const float*)d_in[16];
    const float* Wr5    = (const float*)d_in[17];
    const float* W_out  = (const float*)d_in[18];
    const float* b_out  = (const float*)d_in[19];
    float* out = (float*)d_out;

    const int N = N_NODES, E = N_EDGES;
    const int* e_src = ei;
    const int* e_dst = ei + E;

    size_t off = 0;
    auto carve = [&](size_t bytes) {
        void* p = (char*)d_ws + off;
        off += (bytes + 255) & ~(size_t)255;
        return p;
    };
    int*   offsets  = (int*)carve((size_t)(N + 1) * 4);
    float* inv_deg  = (float*)carve((size_t)N * 4);
    int*   ssrc     = (int*)carve((size_t)E * 4);
    int*   blkCntT  = (int*)carve((size_t)NBUCK * NBUCK * 4);
    int*   blkBaseL = (int*)carve((size_t)NBUCK * NBUCK * 4);
    int*   bucketTotal = (int*)carve((size_t)NBUCK * 4);
    int*   bstart   = (int*)carve((size_t)(NBUCK + 1) * 4);
    int2*  staging  = (int2*)carve((size_t)E * 8);
    unsigned short* Wt = (unsigned short*)carve((size_t)128 * 256 * 2);
    float* agg      = (float*)carve((size_t)N * 128 * 4);
    float* bufA     = (float*)carve((size_t)N * 128 * 4);
    float* bufB     = (float*)carve((size_t)N * 128 * 4);
    unsigned short* g3b = (unsigned short*)carve((size_t)N * 32 * 2);
    unsigned short* h3b = (unsigned short*)carve((size_t)N * 32 * 2);
    unsigned short* h4b = (unsigned short*)carve((size_t)N * 32 * 2);

    float* slotA = agg;
    float* slotB = agg + (size_t)N * 32;
    float* slotC = agg + (size_t)N * 64;
    float* slotD = agg + (size_t)N * 96;
    unsigned short* h1_bf = (unsigned short*)bufA;               // sliced: 8 planes
    unsigned short* aggB  = (unsigned short*)bufA + (size_t)N * 128;  // sliced

    // --- CSR build: 256-bucket counting sort ---
    pa_count<<<NBUCK, 256, 0, stream>>>(e_dst, blkCntT);
    pa_scan1<<<NBUCK, 256, 0, stream>>>(blkCntT, blkBaseL, bucketTotal);
    pa_scan2<<<1, 256, 0, stream>>>(bucketTotal, bstart, offsets);
    pa_scatter<<<NBUCK, 256, 0, stream>>>(e_src, e_dst, blkBaseL, bstart, staging);
    pc_fill<<<NBUCK, 512, 0, stream>>>(staging, bstart, ssrc, offsets, inv_deg);
    prep_wt<<<128, 256, 0, stream>>>(Wl2, Wr2, Wt);

    const int gemm_grid = (N + 127) / 128;

    // --- layer 1: 2 -> 128 (bf16 sliced out) ---
    aggregate2<<<(N + 255) / 256, 256, 0, stream>>>(x, offsets, ssrc, inv_deg, slotA, N);
    sage_linear2<<<(N * 128 + 255) / 256, 256, 0, stream>>>(slotA, x, Wl1, bl1, Wr1, h1_bf, N);

    // --- layer 2: 128 -> 128, sliced bf16 gather + MFMA GEMM ---
    {
        int blocks = 8 * ((N + 127) / 128);
        aggregate_bf128s<<<blocks, 256, 0, stream>>>(h1_bf, offsets, ssrc, inv_deg, aggB, N);
    }
    gemm_l2_mfma<<<gemm_grid, 256, 0, stream>>>(aggB, h1_bf, Wt, bl2, bufB, N);

    // --- layer 3: 128 -> 32, via linearity; bf16 gather ---
    gemm_pre32<128><<<gemm_grid, 256, 0, stream>>>(bufB, Wl3, g3b, N);
    aggregate_bf32<<<(N * 4 + 255) / 256, 256, 0, stream>>>(g3b, offsets, ssrc, inv_deg, slotB, N);
    gemm_post32<128><<<gemm_grid, 256, 0, stream>>>(slotB, bufB, Wr3, bl3, slotC, h3b, N);

    // --- layer 4: 32 -> 32 (bf16 gather) ---
    aggregate_bf32<<<(N * 4 + 255) / 256, 256, 0, stream>>>(h3b, offsets, ssrc, inv_deg, slotD, N);
    gemm_n32<32, true, false><<<gemm_grid, 256, 0, stream>>>(slotD, slotC, Wl4, bl4, Wr4,
                                                             slotA, h4b, nullptr, nullptr,
                                                             nullptr, N);

    // --- layer 5: 32 -> 32, fused final projection ---
    aggregate_bf32<<<(N * 4 + 255) / 256, 256, 0, stream>>>(h4b, offsets, ssrc, inv_deg, slotB, N);
    gemm_n32<32, false, true><<<gemm_grid, 256, 0, stream>>>(slotB, slotA, Wl5, bl5, Wr5,
                                                             nullptr, nullptr, W_out, b_out,
                                                             out, N);
}

// Round 15
// 377.383 us; speedup vs baseline: 1.1660x; 1.1660x over previous
//
#include <hip/hip_runtime.h>
#include <hip/hip_bf16.h>

#define N_NODES 100000
#define N_EDGES 1600000
#define NBUCK 256
#define NODES_PER_BUCKET 391        // 256*391 = 100096 >= 100000
#define EDGES_PER_CHUNK (N_EDGES / NBUCK)   // 6250 exactly
#define FILL_LDS_CAP 8192           // mean 6250, sigma~79 -> +24 sigma

typedef __bf16 bf16x8 __attribute__((ext_vector_type(8)));
typedef float f32x4 __attribute__((ext_vector_type(4)));

// ---------------- helpers ----------------

__device__ inline unsigned short f2bf_rne(float v) {
    unsigned u = __float_as_uint(v);
    u += 0x7fffu + ((u >> 16) & 1u);
    return (unsigned short)(u >> 16);
}

__device__ inline unsigned pack_bf(float a, float b) {
    return (unsigned)f2bf_rne(a) | ((unsigned)f2bf_rne(b) << 16);
}

__device__ inline void acc8_bf(float* a, uint4 p) {
    a[0] += __uint_as_float(p.x << 16);
    a[1] += __uint_as_float(p.x & 0xffff0000u);
    a[2] += __uint_as_float(p.y << 16);
    a[3] += __uint_as_float(p.y & 0xffff0000u);
    a[4] += __uint_as_float(p.z << 16);
    a[5] += __uint_as_float(p.z & 0xffff0000u);
    a[6] += __uint_as_float(p.w << 16);
    a[7] += __uint_as_float(p.w & 0xffff0000u);
}

// ---------------- CSR build: 256-bucket counting sort, coalesced writes ----

__global__ __launch_bounds__(256) void pa_count(const int* __restrict__ dst,
                                                int* __restrict__ blkCntT) {
    __shared__ int hist[NBUCK];
    hist[threadIdx.x] = 0;
    __syncthreads();
    int b0 = blockIdx.x * EDGES_PER_CHUNK;
    int b1 = min(b0 + EDGES_PER_CHUNK, N_EDGES);
    for (int i = b0 + (int)threadIdx.x; i < b1; i += 256) {
        int d = __builtin_nontemporal_load(&dst[i]);
        atomicAdd(&hist[d / NODES_PER_BUCKET], 1);
    }
    __syncthreads();
    blkCntT[threadIdx.x * NBUCK + blockIdx.x] = hist[threadIdx.x];
}

__global__ __launch_bounds__(256) void pa_scan1(const int* __restrict__ blkCntT,
                                                int* __restrict__ blkBaseL,
                                                int* __restrict__ bucketTotal) {
    __shared__ int s[256];
    int t = threadIdx.x;
    int v = blkCntT[blockIdx.x * NBUCK + t];
    s[t] = v;
    __syncthreads();
    for (int off = 1; off < 256; off <<= 1) {
        int u = (t >= off) ? s[t - off] : 0;
        __syncthreads();
        s[t] += u;
        __syncthreads();
    }
    blkBaseL[blockIdx.x * NBUCK + t] = s[t] - v;
    if (t == 255) bucketTotal[blockIdx.x] = s[255];
}

__global__ __launch_bounds__(256) void pa_scan2(const int* __restrict__ bucketTotal,
                                                int* __restrict__ bstart,
                                                int* __restrict__ offsets) {
    __shared__ int s[256];
    int t = threadIdx.x;
    int v = bucketTotal[t];
    s[t] = v;
    __syncthreads();
    for (int off = 1; off < 256; off <<= 1) {
        int u = (t >= off) ? s[t - off] : 0;
        __syncthreads();
        s[t] += u;
        __syncthreads();
    }
    bstart[t] = s[t] - v;
    if (t == 255) {
        bstart[256] = s[255];
        offsets[N_NODES] = s[255];
    }
}

__global__ __launch_bounds__(256) void pa_scatter(const int* __restrict__ src,
                                                  const int* __restrict__ dst,
                                                  const int* __restrict__ blkBaseL,
                                                  const int* __restrict__ bstart,
                                                  int2* __restrict__ staging) {
    __shared__ int hist[NBUCK];
    __shared__ int runStart[NBUCK];
    __shared__ int cur[NBUCK];
    __shared__ int gbase[NBUCK];
    __shared__ int2 buf[EDGES_PER_CHUNK];

    const int tid = threadIdx.x;
    const int g = blockIdx.x;
    const int b0 = g * EDGES_PER_CHUNK;
    const int b1 = min(b0 + EDGES_PER_CHUNK, N_EDGES);

    hist[tid] = 0;
    __syncthreads();
    for (int i = b0 + tid; i < b1; i += 256) {
        int d = __builtin_nontemporal_load(&dst[i]);
        atomicAdd(&hist[d / NODES_PER_BUCKET], 1);
    }
    __syncthreads();
    {
        __shared__ int s[256];
        int v = hist[tid];
        s[tid] = v;
        __syncthreads();
        for (int off = 1; off < 256; off <<= 1) {
            int u = (tid >= off) ? s[tid - off] : 0;
            __syncthreads();
            s[tid] += u;
            __syncthreads();
        }
        runStart[tid] = s[tid] - v;
        cur[tid] = s[tid] - v;
        gbase[tid] = bstart[tid] + blkBaseL[tid * NBUCK + g];
    }
    __syncthreads();
    for (int i = b0 + tid; i < b1; i += 256) {
        int d = __builtin_nontemporal_load(&dst[i]);
        int s_ = __builtin_nontemporal_load(&src[i]);
        int k = d / NODES_PER_BUCKET;
        int p = atomicAdd(&cur[k], 1);
        buf[p] = make_int2(s_, d);
    }
    __syncthreads();
    int cnt = b1 - b0;
    for (int i = tid; i < cnt; i += 256) {
        int2 e = buf[i];
        int k = e.y / NODES_PER_BUCKET;
        staging[gbase[k] + (i - runStart[k])] = e;
    }
}

__global__ __launch_bounds__(512) void pc_fill(const int2* __restrict__ staging,
                                               const int* __restrict__ bstart,
                                               int* __restrict__ ssrc,
                                               int* __restrict__ offsets,
                                               float* __restrict__ inv_deg) {
    __shared__ int scnt[NODES_PER_BUCKET];
    __shared__ int sexc[NODES_PER_BUCKET];
    __shared__ int scur[NODES_PER_BUCKET];
    __shared__ int ssrcL[FILL_LDS_CAP];

    const int tid = threadIdx.x;
    const int b = blockIdx.x;
    const int node0 = b * NODES_PER_BUCKET;
    const int nn = min(node0 + NODES_PER_BUCKET, N_NODES) - node0;
    if (nn <= 0) return;
    const int es = bstart[b], ee = bstart[b + 1];
    const int cnt = ee - es;

    for (int j = tid; j < nn; j += 512) scnt[j] = 0;
    __syncthreads();
    for (int i = es + tid; i < ee; i += 512) {
        int2 e = staging[i];
        atomicAdd(&scnt[e.y - node0], 1);
    }
    __syncthreads();

    if (tid < 64) {
        int base = tid * 7;
        int vals[7];
        int run = 0;
#pragma unroll
        for (int j = 0; j < 7; ++j) {
            int idx = base + j;
            int c = (idx < nn) ? scnt[idx] : 0;
            vals[j] = run;
            run += c;
        }
        int inc = run;
#pragma unroll
        for (int off = 1; off < 64; off <<= 1) {
            int u = __shfl_up(inc, off, 64);
            if (tid >= off) inc += u;
        }
        int laneExcl = inc - run;
#pragma unroll
        for (int j = 0; j < 7; ++j) {
            int idx = base + j;
            if (idx < nn) sexc[idx] = laneExcl + vals[j];
        }
    }
    __syncthreads();

    for (int j = tid; j < nn; j += 512) {
        int c = scnt[j];
        int ex = sexc[j];
        offsets[node0 + j] = es + ex;
        inv_deg[node0 + j] = 1.0f / (float)max(c, 1);
        scur[j] = ex;
    }
    __syncthreads();

    if (cnt <= FILL_LDS_CAP) {
        for (int i = es + tid; i < ee; i += 512) {
            int2 e = staging[i];
            int p = atomicAdd(&scur[e.y - node0], 1);
            ssrcL[p] = e.x;
        }
        __syncthreads();
        for (int i = tid; i < cnt; i += 512) ssrc[es + i] = ssrcL[i];
    } else {
        for (int i = es + tid; i < ee; i += 512) {
            int2 e = staging[i];
            int p = atomicAdd(&scur[e.y - node0], 1);
            ssrc[es + p] = e.x;
        }
    }
}

// ---------------- aggregation (R13 contiguous layouts) ----------------

__global__ __launch_bounds__(256) void aggregate_bf128(const unsigned short* __restrict__ hb,
                                                       const int* __restrict__ offs,
                                                       const int* __restrict__ ssrc,
                                                       const float* __restrict__ inv_deg,
                                                       unsigned short* __restrict__ aggb,
                                                       int nnodes) {
    int t = blockIdx.x * 256 + threadIdx.x;
    if (t >= nnodes * 16) return;
    int node = t >> 4;
    int c = t & 15;
    int b = offs[node], e = offs[node + 1];
    const uint4* __restrict__ hb4 = (const uint4*)hb;
    float acc[8] = {0.f, 0.f, 0.f, 0.f, 0.f, 0.f, 0.f, 0.f};
    int i = b;
    for (; i + 4 <= e; i += 4) {
        uint4 p0 = hb4[(size_t)ssrc[i] * 16 + c];
        uint4 p1 = hb4[(size_t)ssrc[i + 1] * 16 + c];
        uint4 p2 = hb4[(size_t)ssrc[i + 2] * 16 + c];
        uint4 p3 = hb4[(size_t)ssrc[i + 3] * 16 + c];
        acc8_bf(acc, p0);
        acc8_bf(acc, p1);
        acc8_bf(acc, p2);
        acc8_bf(acc, p3);
    }
    for (; i < e; ++i) {
        uint4 p = hb4[(size_t)ssrc[i] * 16 + c];
        acc8_bf(acc, p);
    }
    float s = inv_deg[node];
    uint4 o;
    o.x = pack_bf(acc[0] * s, acc[1] * s);
    o.y = pack_bf(acc[2] * s, acc[3] * s);
    o.z = pack_bf(acc[4] * s, acc[5] * s);
    o.w = pack_bf(acc[6] * s, acc[7] * s);
    ((uint4*)aggb)[t] = o;
}

__global__ __launch_bounds__(256) void aggregate_bf32(const unsigned short* __restrict__ hb,
                                                      const int* __restrict__ offs,
                                                      const int* __restrict__ ssrc,
                                                      const float* __restrict__ inv_deg,
                                                      float* __restrict__ agg, int nnodes) {
    int t = blockIdx.x * 256 + threadIdx.x;
    if (t >= nnodes * 4) return;
    int node = t >> 2;
    int c = t & 3;
    int b = offs[node], e = offs[node + 1];
    const uint4* __restrict__ hb4 = (const uint4*)hb;
    float acc[8] = {0.f, 0.f, 0.f, 0.f, 0.f, 0.f, 0.f, 0.f};
    int i = b;
    for (; i + 4 <= e; i += 4) {
        uint4 p0 = hb4[(size_t)ssrc[i] * 4 + c];
        uint4 p1 = hb4[(size_t)ssrc[i + 1] * 4 + c];
        uint4 p2 = hb4[(size_t)ssrc[i + 2] * 4 + c];
        uint4 p3 = hb4[(size_t)ssrc[i + 3] * 4 + c];
        acc8_bf(acc, p0);
        acc8_bf(acc, p1);
        acc8_bf(acc, p2);
        acc8_bf(acc, p3);
    }
    for (; i < e; ++i) {
        uint4 p = hb4[(size_t)ssrc[i] * 4 + c];
        acc8_bf(acc, p);
    }
    float s = inv_deg[node];
    float4* outp = (float4*)&agg[(size_t)node * 32 + c * 8];
    outp[0] = make_float4(acc[0] * s, acc[1] * s, acc[2] * s, acc[3] * s);
    outp[1] = make_float4(acc[4] * s, acc[5] * s, acc[6] * s, acc[7] * s);
}

__global__ __launch_bounds__(256) void aggregate2(const float* __restrict__ h,
                                                  const int* __restrict__ offs,
                                                  const int* __restrict__ ssrc,
                                                  const float* __restrict__ inv_deg,
                                                  float* __restrict__ agg, int nnodes) {
    int node = blockIdx.x * blockDim.x + threadIdx.x;
    if (node >= nnodes) return;
    int b = offs[node], e = offs[node + 1];
    const float2* __restrict__ h2 = (const float2*)h;
    float2 a0 = make_float2(0.f, 0.f), a1 = make_float2(0.f, 0.f);
    int i = b;
    for (; i + 2 <= e; i += 2) {
        float2 v = h2[ssrc[i]];
        float2 w = h2[ssrc[i + 1]];
        a0.x += v.x; a0.y += v.y;
        a1.x += w.x; a1.y += w.y;
    }
    if (i < e) {
        float2 v = h2[ssrc[i]];
        a0.x += v.x; a0.y += v.y;
    }
    float s = inv_deg[node];
    ((float2*)agg)[node] = make_float2((a0.x + a1.x) * s, (a0.y + a1.y) * s);
}

// ---------------- weight prep ----------------

__global__ __launch_bounds__(256) void prep_wt(const float* __restrict__ Wl,
                                               const float* __restrict__ Wr,
                                               unsigned short* __restrict__ Wt) {
    int idx = blockIdx.x * 256 + threadIdx.x;
    int n = idx >> 8;
    int k = idx & 255;
    float v = (k < 128) ? Wl[k * 128 + n] : Wr[(k - 128) * 128 + n];
    Wt[idx] = f2bf_rne(v);
}

// W3c[n][k] bf16, n<32: Wl3^T, n in 32..63: Wr3^T  (64 x 128)
__global__ __launch_bounds__(256) void prep_w3(const float* __restrict__ Wl3,
                                               const float* __restrict__ Wr3,
                                               unsigned short* __restrict__ W3c) {
    int idx = blockIdx.x * 256 + threadIdx.x;
    if (idx >= 64 * 128) return;
    int n = idx >> 7;
    int k = idx & 127;
    float v = (n < 32) ? Wl3[k * 32 + n] : Wr3[k * 32 + (n - 32)];
    W3c[idx] = f2bf_rne(v);
}

// ---------------- layer-2 MFMA GEMM + fused layer-3 products ----------------
// Main: h2 = relu([agg|h1] @ [Wl2;Wr2] + bl2), 128x128 tile, never written.
// Epilogue: h2 tile -> LDS bf16; second MFMA GEMM vs W3c gives
//   g3 = h2@Wl3 (bf16 out, gather operand) and p3 = h2@Wr3 (fp32 out).

__global__ __launch_bounds__(256) void gemm_l2_mfma(const unsigned short* __restrict__ Ab,
                                                    const unsigned short* __restrict__ Hb,
                                                    const unsigned short* __restrict__ Wt,
                                                    const float* __restrict__ bias,
                                                    const unsigned short* __restrict__ W3c,
                                                    unsigned short* __restrict__ g3b,
                                                    float* __restrict__ p3, int M) {
    constexpr int BM = 128, BK = 64;
    // main phase: sA,sB = 2 x [128][72]; epilogue: sH [128][136] + sW3 [64][136]
    __shared__ unsigned short smem[26112];
#define SA(r, c) smem[(r) * 72 + (c)]
#define SB(r, c) smem[9216 + (r) * 72 + (c)]
#define SH(r, c) smem[(r) * 136 + (c)]
#define SW3(r, c) smem[17408 + (r) * 136 + (c)]

    const int tid = threadIdx.x;
    const int m0 = blockIdx.x * BM;
    const int lane = tid & 63;
    const int wid = tid >> 6;
    const int l15 = lane & 15;
    const int quad = lane >> 4;
    const int wm = (wid >> 1) * 64;
    const int wn = (wid & 1) * 64;

    f32x4 acc[4][4];
#pragma unroll
    for (int i = 0; i < 4; ++i)
#pragma unroll
        for (int j = 0; j < 4; ++j) acc[i][j] = (f32x4){0.f, 0.f, 0.f, 0.f};

    for (int k0 = 0; k0 < 256; k0 += BK) {
        const uint4* __restrict__ srcA = (const uint4*)((k0 < 128) ? Ab : Hb);
        const int kc = (k0 & 64) >> 3;
#pragma unroll
        for (int l = 0; l < 4; ++l) {
            int idx = tid + l * 256;
            int row = idx >> 3;
            int c8 = idx & 7;
            int gr = min(m0 + row, M - 1);
            uint4 va = srcA[(size_t)gr * 16 + kc + c8];
            *(uint4*)&SA(row, c8 * 8) = va;
            uint4 vb = ((const uint4*)Wt)[(size_t)row * 32 + (k0 >> 3) + c8];
            *(uint4*)&SB(row, c8 * 8) = vb;
        }
        __syncthreads();

#pragma unroll
        for (int ks = 0; ks < BK; ks += 32) {
            bf16x8 a[4], b[4];
#pragma unroll
            for (int t = 0; t < 4; ++t) {
                a[t] = *(const bf16x8*)&SA(wm + t * 16 + l15, ks + quad * 8);
                b[t] = *(const bf16x8*)&SB(wn + t * 16 + l15, ks + quad * 8);
            }
#pragma unroll
            for (int i = 0; i < 4; ++i)
#pragma unroll
                for (int j = 0; j < 4; ++j)
                    acc[i][j] = __builtin_amdgcn_mfma_f32_16x16x32_bf16(
                        a[i], b[j], acc[i][j], 0, 0, 0);
        }
        __syncthreads();
    }

    // --- epilogue phase 1: h2 tile (relu+bias) -> SH bf16; stage W3c -> SW3 ---
#pragma unroll
    for (int j = 0; j < 4; ++j) {
        int n = wn + j * 16 + l15;
        float bv = bias[n];
#pragma unroll
        for (int i = 0; i < 4; ++i) {
#pragma unroll
            for (int r = 0; r < 4; ++r) {
                int ml = wm + i * 16 + quad * 4 + r;
                SH(ml, n) = f2bf_rne(fmaxf(acc[i][j][r] + bv, 0.f));
            }
        }
    }
#pragma unroll
    for (int l = 0; l < 4; ++l) {
        int idx = tid + l * 256;          // 0..1023 over 64x16 uint4 chunks
        int row = idx >> 4;
        int c8 = idx & 15;
        uint4 v = ((const uint4*)W3c)[(size_t)row * 16 + c8];
        *(uint4*)&SW3(row, c8 * 8) = v;
    }
    __syncthreads();

    // --- epilogue phase 2: [g3|p3] = h2 @ W3c^T ; wave w owns rows w*32..+31 ---
    f32x4 acc2[2][4];
#pragma unroll
    for (int i = 0; i < 2; ++i)
#pragma unroll
        for (int j = 0; j < 4; ++j) acc2[i][j] = (f32x4){0.f, 0.f, 0.f, 0.f};

#pragma unroll
    for (int ks = 0; ks < 128; ks += 32) {
        bf16x8 a[2], b[4];
#pragma unroll
        for (int i = 0; i < 2; ++i)
            a[i] = *(const bf16x8*)&SH(wid * 32 + i * 16 + l15, ks + quad * 8);
#pragma unroll
        for (int j = 0; j < 4; ++j)
            b[j] = *(const bf16x8*)&SW3(j * 16 + l15, ks + quad * 8);
#pragma unroll
        for (int i = 0; i < 2; ++i)
#pragma unroll
            for (int j = 0; j < 4; ++j)
                acc2[i][j] = __builtin_amdgcn_mfma_f32_16x16x32_bf16(
                    a[i], b[j], acc2[i][j], 0, 0, 0);
    }

#pragma unroll
    for (int i = 0; i < 2; ++i) {
#pragma unroll
        for (int r = 0; r < 4; ++r) {
            int m = m0 + wid * 32 + i * 16 + quad * 4 + r;
            if (m >= M) continue;
#pragma unroll
            for (int j = 0; j < 4; ++j) {
                float v = acc2[i][j][r];
                if (j < 2) g3b[(size_t)m * 32 + j * 16 + l15] = f2bf_rne(v);
                else       p3[(size_t)m * 32 + (j - 2) * 16 + l15] = v;
            }
        }
    }
#undef SA
#undef SB
#undef SH
#undef SW3
}

// layer-3 combine: h3 = relu(agg3 + p3 + bl3); fp32 + bf16 out
__global__ __launch_bounds__(256) void combine3(const float* __restrict__ agg3,
                                                const float* __restrict__ p3,
                                                const float* __restrict__ bias,
                                                float* __restrict__ h3,
                                                unsigned short* __restrict__ h3b,
                                                int nnodes) {
    int idx = blockIdx.x * 256 + threadIdx.x;
    if (idx >= nnodes * 8) return;
    int c4 = idx & 7;
    float4 a = ((const float4*)agg3)[idx];
    float4 p = ((const float4*)p3)[idx];
    float4 bv = *(const float4*)&bias[c4 * 4];
    float4 r;
    r.x = fmaxf(a.x + p.x + bv.x, 0.f);
    r.y = fmaxf(a.y + p.y + bv.y, 0.f);
    r.z = fmaxf(a.z + p.z + bv.z, 0.f);
    r.w = fmaxf(a.w + p.w + bv.w, 0.f);
    ((float4*)h3)[idx] = r;
    uint2 o;
    o.x = pack_bf(r.x, r.y);
    o.y = pack_bf(r.z, r.w);
    ((uint2*)h3b)[idx] = o;
}

// ---------------- Cout=32 GEMMs (layers 4/5) ----------------

template <int Cin, bool EMIT_BF, bool FUSE_OUT>
__global__ __launch_bounds__(256) void gemm_n32(const float* __restrict__ A0,
                                                const float* __restrict__ A1,
                                                const float* __restrict__ W0,
                                                const float* __restrict__ bias,
                                                const float* __restrict__ W1,
                                                float* __restrict__ C,
                                                unsigned short* __restrict__ Cbf,
                                                const float* __restrict__ Wout,
                                                const float* __restrict__ bout,
                                                float* __restrict__ out, int M) {
    constexpr int COUT = 32, BM = 128, BK = 16;
    __shared__ float sA0[BK][BM + 4];
    __shared__ float sA1[BK][BM + 4];
    __shared__ float sW0[BK][36];
    __shared__ float sW1[BK][36];

    const int tid = threadIdx.x;
    const int m0 = blockIdx.x * BM;
    const int tr = tid >> 3;
    const int tc = tid & 7;

    float acc[4][4];
#pragma unroll
    for (int i = 0; i < 4; ++i)
#pragma unroll
        for (int j = 0; j < 4; ++j) acc[i][j] = 0.f;

    const int wrow = tid >> 3;
    const int wc4  = tid & 7;

    for (int k0 = 0; k0 < Cin; k0 += BK) {
#pragma unroll
        for (int l = 0; l < 2; ++l) {
            int idx = tid + l * 256;
            int row = idx >> 2;
            int c4  = idx & 3;
            int gr  = min(m0 + row, M - 1);
            float4 v0 = *(const float4*)&A0[(size_t)gr * Cin + k0 + c4 * 4];
            float4 v1 = *(const float4*)&A1[(size_t)gr * Cin + k0 + c4 * 4];
            sA0[c4 * 4 + 0][row] = v0.x; sA0[c4 * 4 + 1][row] = v0.y;
            sA0[c4 * 4 + 2][row] = v0.z; sA0[c4 * 4 + 3][row] = v0.w;
            sA1[c4 * 4 + 0][row] = v1.x; sA1[c4 * 4 + 1][row] = v1.y;
            sA1[c4 * 4 + 2][row] = v1.z; sA1[c4 * 4 + 3][row] = v1.w;
        }
        if (tid < 128) {
            float4 w0 = *(const float4*)&W0[(size_t)(k0 + wrow) * COUT + wc4 * 4];
            float4 w1 = *(const float4*)&W1[(size_t)(k0 + wrow) * COUT + wc4 * 4];
            *(float4*)&sW0[wrow][wc4 * 4] = w0;
            *(float4*)&sW1[wrow][wc4 * 4] = w1;
        }
        __syncthreads();

#pragma unroll
        for (int k = 0; k < BK; ++k) {
            float4 a0 = *(const float4*)&sA0[k][tr * 4];
            float4 a1 = *(const float4*)&sA1[k][tr * 4];
            float4 w0 = *(const float4*)&sW0[k][tc * 4];
            float4 w1 = *(const float4*)&sW1[k][tc * 4];
            float av0[4] = {a0.x, a0.y, a0.z, a0.w};
            float av1[4] = {a1.x, a1.y, a1.z, a1.w};
            float wv0[4] = {w0.x, w0.y, w0.z, w0.w};
            float wv1[4] = {w1.x, w1.y, w1.z, w1.w};
#pragma unroll
            for (int i = 0; i < 4; ++i)
#pragma unroll
                for (int j = 0; j < 4; ++j)
                    acc[i][j] = fmaf(av0[i], wv0[j], fmaf(av1[i], wv1[j], acc[i][j]));
        }
        __syncthreads();
    }

#pragma unroll
    for (int i = 0; i < 4; ++i) {
        int m = m0 + tr * 4 + i;
        if (m >= M) continue;
        int n = tc * 4;
        float4 bv = *(const float4*)&bias[n];
        float4 r;
        r.x = fmaxf(acc[i][0] + bv.x, 0.f);
        r.y = fmaxf(acc[i][1] + bv.y, 0.f);
        r.z = fmaxf(acc[i][2] + bv.z, 0.f);
        r.w = fmaxf(acc[i][3] + bv.w, 0.f);
        if (FUSE_OUT) {
            float p = r.x * Wout[n] + r.y * Wout[n + 1] +
                      r.z * Wout[n + 2] + r.w * Wout[n + 3];
            p += __shfl_down(p, 4, 8);
            p += __shfl_down(p, 2, 8);
            p += __shfl_down(p, 1, 8);
            if (tc == 0) out[m] = p + bout[0];
        } else {
            *(float4*)&C[(size_t)m * COUT + n] = r;
            if (EMIT_BF) {
                uint2 o;
                o.x = pack_bf(r.x, r.y);
                o.y = pack_bf(r.z, r.w);
                *(uint2*)&Cbf[(size_t)m * COUT + n] = o;
            }
        }
    }
}

// layer-1 linear (Cin=2): contiguous bf16 out
__global__ __launch_bounds__(256) void sage_linear2(const float* __restrict__ agg,
                                                    const float* __restrict__ h,
                                                    const float* __restrict__ Wl,
                                                    const float* __restrict__ bl,
                                                    const float* __restrict__ Wr,
                                                    unsigned short* __restrict__ out_bf,
                                                    int nnodes) {
    constexpr int Cout = 128;
    int t = blockIdx.x * blockDim.x + threadIdx.x;
    if (t >= nnodes * Cout) return;
    int node = t / Cout;
    int c = t - node * Cout;
    float2 a = ((const float2*)agg)[node];
    float2 hh = ((const float2*)h)[node];
    float acc = bl[c];
    acc = fmaf(a.x, Wl[c], acc);
    acc = fmaf(a.y, Wl[Cout + c], acc);
    acc = fmaf(hh.x, Wr[c], acc);
    acc = fmaf(hh.y, Wr[Cout + c], acc);
    acc = fmaxf(acc, 0.f);
    out_bf[t] = f2bf_rne(acc);
}

// ---------------- launch ----------------

extern "C" void kernel_launch(void* const* d_in, const int* in_sizes, int n_in,
                              void* d_out, int out_size, void* d_ws, size_t ws_size,
                              hipStream_t stream) {
    const float* x      = (const float*)d_in[0];
    const int*   ei     = (const int*)d_in[1];
    const float* Wl1    = (const float*)d_in[3];
    const float* bl1    = (const float*)d_in[4];
    const float* Wr1    = (const float*)d_in[5];
    const float* Wl2    = (const float*)d_in[6];
    const float* bl2    = (const float*)d_in[7];
    const float* Wr2    = (const float*)d_in[8];
    const float* Wl3    = (const float*)d_in[9];
    const float* bl3    = (const float*)d_in[10];
    const float* Wr3    = (const float*)d_in[11];
    const float* Wl4    = (const float*)d_in[12];
    const float* bl4    = (const float*)d_in[13];
    const float* Wr4    = (const float*)d_in[14];
    const float* Wl5    = (const float*)d_in[15];
    const float* bl5    = (const float*)d_in[16];
    const float* Wr5    = (const float*)d_in[17];
    const float* W_out  = (const float*)d_in[18];
    const float* b_out  = (const float*)d_in[19];
    float* out = (float*)d_out;

    const int N = N_NODES, E = N_EDGES;
    const int* e_src = ei;
    const int* e_dst = ei + E;

    size_t off = 0;
    auto carve = [&](size_t bytes) {
        void* p = (char*)d_ws + off;
        off += (bytes + 255) & ~(size_t)255;
        return p;
    };
    int*   offsets  = (int*)carve((size_t)(N + 1) * 4);
    float* inv_deg  = (float*)carve((size_t)N * 4);
    int*   ssrc     = (int*)carve((size_t)E * 4);
    int*   blkCntT  = (int*)carve((size_t)NBUCK * NBUCK * 4);
    int*   blkBaseL = (int*)carve((size_t)NBUCK * NBUCK * 4);
    int*   bucketTotal = (int*)carve((size_t)NBUCK * 4);
    int*   bstart   = (int*)carve((size_t)(NBUCK + 1) * 4);
    int2*  staging  = (int2*)carve((size_t)E * 8);
    unsigned short* Wt  = (unsigned short*)carve((size_t)128 * 256 * 2);
    unsigned short* W3c = (unsigned short*)carve((size_t)64 * 128 * 2);
    float* agg      = (float*)carve((size_t)N * 128 * 4);   // 4x (N x 32) fp32 slots
    float* bufA     = (float*)carve((size_t)N * 128 * 4);   // 2x (N x 128) bf16
    unsigned short* g3b = (unsigned short*)carve((size_t)N * 32 * 2);
    unsigned short* h3b = (unsigned short*)carve((size_t)N * 32 * 2);
    unsigned short* h4b = (unsigned short*)carve((size_t)N * 32 * 2);

    float* slotA = agg;                       // p3, later h4
    float* slotB = agg + (size_t)N * 32;      // agg3 / agg5
    float* slotC = agg + (size_t)N * 64;      // h3 / (layer1 agg scratch)
    float* slotD = agg + (size_t)N * 96;      // agg4
    unsigned short* h1_bf = (unsigned short*)bufA;
    unsigned short* aggB  = (unsigned short*)bufA + (size_t)N * 128;

    // --- CSR build: 256-bucket counting sort ---
    pa_count<<<NBUCK, 256, 0, stream>>>(e_dst, blkCntT);
    pa_scan1<<<NBUCK, 256, 0, stream>>>(blkCntT, blkBaseL, bucketTotal);
    pa_scan2<<<1, 256, 0, stream>>>(bucketTotal, bstart, offsets);
    pa_scatter<<<NBUCK, 256, 0, stream>>>(e_src, e_dst, blkBaseL, bstart, staging);
    pc_fill<<<NBUCK, 512, 0, stream>>>(staging, bstart, ssrc, offsets, inv_deg);
    prep_wt<<<128, 256, 0, stream>>>(Wl2, Wr2, Wt);
    prep_w3<<<32, 256, 0, stream>>>(Wl3, Wr3, W3c);

    const int gemm_grid = (N + 127) / 128;

    // --- layer 1: 2 -> 128 (bf16 out) ---
    aggregate2<<<(N + 255) / 256, 256, 0, stream>>>(x, offsets, ssrc, inv_deg, slotC, N);
    sage_linear2<<<(N * 128 + 255) / 256, 256, 0, stream>>>(slotC, x, Wl1, bl1, Wr1, h1_bf, N);

    // --- layer 2 + layer-3 products: bf16 gather + fused MFMA GEMM ---
    aggregate_bf128<<<(N * 16 + 255) / 256, 256, 0, stream>>>(h1_bf, offsets, ssrc,
                                                              inv_deg, aggB, N);
    gemm_l2_mfma<<<gemm_grid, 256, 0, stream>>>(aggB, h1_bf, Wt, bl2, W3c, g3b, slotA, N);

    // --- layer 3 finish: gather g3, combine with p3 ---
    aggregate_bf32<<<(N * 4 + 255) / 256, 256, 0, stream>>>(g3b, offsets, ssrc, inv_deg, slotB, N);
    combine3<<<(N * 8 + 255) / 256, 256, 0, stream>>>(slotB, slotA, bl3, slotC, h3b, N);

    // --- layer 4: 32 -> 32 (bf16 gather) ---
    aggregate_bf32<<<(N * 4 + 255) / 256, 256, 0, stream>>>(h3b, offsets, ssrc, inv_deg, slotD, N);
    gemm_n32<32, true, false><<<gemm_grid, 256, 0, stream>>>(slotD, slotC, Wl4, bl4, Wr4,
                                                             slotA, h4b, nullptr, nullptr,
                                                             nullptr, N);

    // --- layer 5: 32 -> 32, fused final projection ---
    aggregate_bf32<<<(N * 4 + 255) / 256, 256, 0, stream>>>(h4b, offsets, ssrc, inv_deg, slotB, N);
    gemm_n32<32, false, true><<<gemm_grid, 256, 0, stream>>>(slotB, slotA, Wl5, bl5, Wr5,
                                                             nullptr, nullptr, W_out, b_out,
                                                             out, N);
}

// Round 16
// 372.454 us; speedup vs baseline: 1.1815x; 1.0132x over previous
//
#include <hip/hip_runtime.h>
#include <hip/hip_bf16.h>

#define N_NODES 100000
#define N_EDGES 1600000
#define NBUCK 256
#define NODES_PER_BUCKET 391        // 256*391 = 100096 >= 100000
#define EDGES_PER_CHUNK (N_EDGES / NBUCK)   // 6250 exactly
#define FILL_LDS_CAP 8192           // mean 6250, sigma~79 -> +24 sigma

typedef __bf16 bf16x8 __attribute__((ext_vector_type(8)));
typedef float f32x4 __attribute__((ext_vector_type(4)));

// ---------------- helpers ----------------

__device__ inline unsigned short f2bf_rne(float v) {
    unsigned u = __float_as_uint(v);
    u += 0x7fffu + ((u >> 16) & 1u);
    return (unsigned short)(u >> 16);
}

__device__ inline unsigned pack_bf(float a, float b) {
    return (unsigned)f2bf_rne(a) | ((unsigned)f2bf_rne(b) << 16);
}

__device__ inline void acc8_bf(float* a, uint4 p) {
    a[0] += __uint_as_float(p.x << 16);
    a[1] += __uint_as_float(p.x & 0xffff0000u);
    a[2] += __uint_as_float(p.y << 16);
    a[3] += __uint_as_float(p.y & 0xffff0000u);
    a[4] += __uint_as_float(p.z << 16);
    a[5] += __uint_as_float(p.z & 0xffff0000u);
    a[6] += __uint_as_float(p.w << 16);
    a[7] += __uint_as_float(p.w & 0xffff0000u);
}

// ---------------- CSR build: 256-bucket counting sort, coalesced writes ----

__global__ __launch_bounds__(256) void pa_count(const int* __restrict__ dst,
                                                int* __restrict__ blkCntT) {
    __shared__ int hist[NBUCK];
    hist[threadIdx.x] = 0;
    __syncthreads();
    int b0 = blockIdx.x * EDGES_PER_CHUNK;
    int b1 = min(b0 + EDGES_PER_CHUNK, N_EDGES);
    for (int i = b0 + (int)threadIdx.x; i < b1; i += 256) {
        int d = __builtin_nontemporal_load(&dst[i]);
        atomicAdd(&hist[d / NODES_PER_BUCKET], 1);
    }
    __syncthreads();
    blkCntT[threadIdx.x * NBUCK + blockIdx.x] = hist[threadIdx.x];
}

__global__ __launch_bounds__(256) void pa_scan1(const int* __restrict__ blkCntT,
                                                int* __restrict__ blkBaseL,
                                                int* __restrict__ bucketTotal) {
    __shared__ int s[256];
    int t = threadIdx.x;
    int v = blkCntT[blockIdx.x * NBUCK + t];
    s[t] = v;
    __syncthreads();
    for (int off = 1; off < 256; off <<= 1) {
        int u = (t >= off) ? s[t - off] : 0;
        __syncthreads();
        s[t] += u;
        __syncthreads();
    }
    blkBaseL[blockIdx.x * NBUCK + t] = s[t] - v;
    if (t == 255) bucketTotal[blockIdx.x] = s[255];
}

__global__ __launch_bounds__(256) void pa_scan2(const int* __restrict__ bucketTotal,
                                                int* __restrict__ bstart,
                                                int* __restrict__ offsets) {
    __shared__ int s[256];
    int t = threadIdx.x;
    int v = bucketTotal[t];
    s[t] = v;
    __syncthreads();
    for (int off = 1; off < 256; off <<= 1) {
        int u = (t >= off) ? s[t - off] : 0;
        __syncthreads();
        s[t] += u;
        __syncthreads();
    }
    bstart[t] = s[t] - v;
    if (t == 255) {
        bstart[256] = s[255];
        offsets[N_NODES] = s[255];
    }
}

// histogram loaded from blkCntT (pa_count already did it) -> one less dst pass
__global__ __launch_bounds__(256) void pa_scatter(const int* __restrict__ src,
                                                  const int* __restrict__ dst,
                                                  const int* __restrict__ blkCntT,
                                                  const int* __restrict__ blkBaseL,
                                                  const int* __restrict__ bstart,
                                                  int2* __restrict__ staging) {
    __shared__ int runStart[NBUCK];
    __shared__ int cur[NBUCK];
    __shared__ int gbase[NBUCK];
    __shared__ int2 buf[EDGES_PER_CHUNK];

    const int tid = threadIdx.x;
    const int g = blockIdx.x;
    const int b0 = g * EDGES_PER_CHUNK;
    const int b1 = min(b0 + EDGES_PER_CHUNK, N_EDGES);

    {
        __shared__ int s[256];
        int v = blkCntT[tid * NBUCK + g];
        s[tid] = v;
        __syncthreads();
        for (int off = 1; off < 256; off <<= 1) {
            int u = (tid >= off) ? s[tid - off] : 0;
            __syncthreads();
            s[tid] += u;
            __syncthreads();
        }
        runStart[tid] = s[tid] - v;
        cur[tid] = s[tid] - v;
        gbase[tid] = bstart[tid] + blkBaseL[tid * NBUCK + g];
    }
    __syncthreads();
    for (int i = b0 + tid; i < b1; i += 256) {
        int d = __builtin_nontemporal_load(&dst[i]);
        int s_ = __builtin_nontemporal_load(&src[i]);
        int k = d / NODES_PER_BUCKET;
        int p = atomicAdd(&cur[k], 1);
        buf[p] = make_int2(s_, d);
    }
    __syncthreads();
    int cnt = b1 - b0;
    for (int i = tid; i < cnt; i += 256) {
        int2 e = buf[i];
        int k = e.y / NODES_PER_BUCKET;
        staging[gbase[k] + (i - runStart[k])] = e;
    }
}

__global__ __launch_bounds__(512) void pc_fill(const int2* __restrict__ staging,
                                               const int* __restrict__ bstart,
                                               int* __restrict__ ssrc,
                                               int* __restrict__ offsets,
                                               float* __restrict__ inv_deg) {
    __shared__ int scnt[NODES_PER_BUCKET];
    __shared__ int sexc[NODES_PER_BUCKET];
    __shared__ int scur[NODES_PER_BUCKET];
    __shared__ int ssrcL[FILL_LDS_CAP];

    const int tid = threadIdx.x;
    const int b = blockIdx.x;
    const int node0 = b * NODES_PER_BUCKET;
    const int nn = min(node0 + NODES_PER_BUCKET, N_NODES) - node0;
    if (nn <= 0) return;
    const int es = bstart[b], ee = bstart[b + 1];
    const int cnt = ee - es;

    for (int j = tid; j < nn; j += 512) scnt[j] = 0;
    __syncthreads();
    for (int i = es + tid; i < ee; i += 512) {
        int2 e = staging[i];
        atomicAdd(&scnt[e.y - node0], 1);
    }
    __syncthreads();

    if (tid < 64) {
        int base = tid * 7;
        int vals[7];
        int run = 0;
#pragma unroll
        for (int j = 0; j < 7; ++j) {
            int idx = base + j;
            int c = (idx < nn) ? scnt[idx] : 0;
            vals[j] = run;
            run += c;
        }
        int inc = run;
#pragma unroll
        for (int off = 1; off < 64; off <<= 1) {
            int u = __shfl_up(inc, off, 64);
            if (tid >= off) inc += u;
        }
        int laneExcl = inc - run;
#pragma unroll
        for (int j = 0; j < 7; ++j) {
            int idx = base + j;
            if (idx < nn) sexc[idx] = laneExcl + vals[j];
        }
    }
    __syncthreads();

    for (int j = tid; j < nn; j += 512) {
        int c = scnt[j];
        int ex = sexc[j];
        offsets[node0 + j] = es + ex;
        inv_deg[node0 + j] = 1.0f / (float)max(c, 1);
        scur[j] = ex;
    }
    __syncthreads();

    if (cnt <= FILL_LDS_CAP) {
        for (int i = es + tid; i < ee; i += 512) {
            int2 e = staging[i];
            int p = atomicAdd(&scur[e.y - node0], 1);
            ssrcL[p] = e.x;
        }
        __syncthreads();
        for (int i = tid; i < cnt; i += 512) ssrc[es + i] = ssrcL[i];
    } else {
        for (int i = es + tid; i < ee; i += 512) {
            int2 e = staging[i];
            int p = atomicAdd(&scur[e.y - node0], 1);
            ssrc[es + p] = e.x;
        }
    }
}

// ---------------- aggregation ----------------

__global__ __launch_bounds__(256) void aggregate_bf128(const unsigned short* __restrict__ hb,
                                                       const int* __restrict__ offs,
                                                       const int* __restrict__ ssrc,
                                                       const float* __restrict__ inv_deg,
                                                       unsigned short* __restrict__ aggb,
                                                       int nnodes) {
    int t = blockIdx.x * 256 + threadIdx.x;
    if (t >= nnodes * 16) return;
    int node = t >> 4;
    int c = t & 15;
    int b = offs[node], e = offs[node + 1];
    const uint4* __restrict__ hb4 = (const uint4*)hb;
    float acc[8] = {0.f, 0.f, 0.f, 0.f, 0.f, 0.f, 0.f, 0.f};
    int i = b;
    for (; i + 4 <= e; i += 4) {
        uint4 p0 = hb4[(size_t)ssrc[i] * 16 + c];
        uint4 p1 = hb4[(size_t)ssrc[i + 1] * 16 + c];
        uint4 p2 = hb4[(size_t)ssrc[i + 2] * 16 + c];
        uint4 p3 = hb4[(size_t)ssrc[i + 3] * 16 + c];
        acc8_bf(acc, p0);
        acc8_bf(acc, p1);
        acc8_bf(acc, p2);
        acc8_bf(acc, p3);
    }
    for (; i < e; ++i) {
        uint4 p = hb4[(size_t)ssrc[i] * 16 + c];
        acc8_bf(acc, p);
    }
    float s = inv_deg[node];
    uint4 o;
    o.x = pack_bf(acc[0] * s, acc[1] * s);
    o.y = pack_bf(acc[2] * s, acc[3] * s);
    o.z = pack_bf(acc[4] * s, acc[5] * s);
    o.w = pack_bf(acc[6] * s, acc[7] * s);
    ((uint4*)aggb)[t] = o;
}

__global__ __launch_bounds__(256) void aggregate_bf32(const unsigned short* __restrict__ hb,
                                                      const int* __restrict__ offs,
                                                      const int* __restrict__ ssrc,
                                                      const float* __restrict__ inv_deg,
                                                      float* __restrict__ agg, int nnodes) {
    int t = blockIdx.x * 256 + threadIdx.x;
    if (t >= nnodes * 4) return;
    int node = t >> 2;
    int c = t & 3;
    int b = offs[node], e = offs[node + 1];
    const uint4* __restrict__ hb4 = (const uint4*)hb;
    float acc[8] = {0.f, 0.f, 0.f, 0.f, 0.f, 0.f, 0.f, 0.f};
    int i = b;
    for (; i + 4 <= e; i += 4) {
        uint4 p0 = hb4[(size_t)ssrc[i] * 4 + c];
        uint4 p1 = hb4[(size_t)ssrc[i + 1] * 4 + c];
        uint4 p2 = hb4[(size_t)ssrc[i + 2] * 4 + c];
        uint4 p3 = hb4[(size_t)ssrc[i + 3] * 4 + c];
        acc8_bf(acc, p0);
        acc8_bf(acc, p1);
        acc8_bf(acc, p2);
        acc8_bf(acc, p3);
    }
    for (; i < e; ++i) {
        uint4 p = hb4[(size_t)ssrc[i] * 4 + c];
        acc8_bf(acc, p);
    }
    float s = inv_deg[node];
    float4* outp = (float4*)&agg[(size_t)node * 32 + c * 8];
    outp[0] = make_float4(acc[0] * s, acc[1] * s, acc[2] * s, acc[3] * s);
    outp[1] = make_float4(acc[4] * s, acc[5] * s, acc[6] * s, acc[7] * s);
}

__global__ __launch_bounds__(256) void aggregate2(const float* __restrict__ h,
                                                  const int* __restrict__ offs,
                                                  const int* __restrict__ ssrc,
                                                  const float* __restrict__ inv_deg,
                                                  float* __restrict__ agg, int nnodes) {
    int node = blockIdx.x * blockDim.x + threadIdx.x;
    if (node >= nnodes) return;
    int b = offs[node], e = offs[node + 1];
    const float2* __restrict__ h2 = (const float2*)h;
    float2 a0 = make_float2(0.f, 0.f), a1 = make_float2(0.f, 0.f);
    int i = b;
    for (; i + 2 <= e; i += 2) {
        float2 v = h2[ssrc[i]];
        float2 w = h2[ssrc[i + 1]];
        a0.x += v.x; a0.y += v.y;
        a1.x += w.x; a1.y += w.y;
    }
    if (i < e) {
        float2 v = h2[ssrc[i]];
        a0.x += v.x; a0.y += v.y;
    }
    float s = inv_deg[node];
    ((float2*)agg)[node] = make_float2((a0.x + a1.x) * s, (a0.y + a1.y) * s);
}

// ---------------- weight prep ----------------

__global__ __launch_bounds__(256) void prep_wt(const float* __restrict__ Wl,
                                               const float* __restrict__ Wr,
                                               unsigned short* __restrict__ Wt) {
    int idx = blockIdx.x * 256 + threadIdx.x;
    int n = idx >> 8;
    int k = idx & 255;
    float v = (k < 128) ? Wl[k * 128 + n] : Wr[(k - 128) * 128 + n];
    Wt[idx] = f2bf_rne(v);
}

// W3c[n][k] bf16 (64 x 128): n<32 -> Wl3^T, else Wr3^T
__global__ __launch_bounds__(256) void prep_w3(const float* __restrict__ Wl3,
                                               const float* __restrict__ Wr3,
                                               unsigned short* __restrict__ W3c) {
    int idx = blockIdx.x * 256 + threadIdx.x;
    if (idx >= 64 * 128) return;
    int n = idx >> 7;
    int k = idx & 127;
    float v = (n < 32) ? Wl3[k * 32 + n] : Wr3[k * 32 + (n - 32)];
    W3c[idx] = f2bf_rne(v);
}

// Wc[n][k] bf16 (64 x 32): n<32 -> Wl^T, else Wr^T   (layers 4, 5)
__global__ __launch_bounds__(256) void prep_w32(const float* __restrict__ Wl,
                                                const float* __restrict__ Wr,
                                                unsigned short* __restrict__ Wc) {
    int idx = blockIdx.x * 256 + threadIdx.x;
    if (idx >= 64 * 32) return;
    int n = idx >> 5;
    int k = idx & 31;
    float v = (n < 32) ? Wl[k * 32 + n] : Wr[k * 32 + (n - 32)];
    Wc[idx] = f2bf_rne(v);
}

// ---------------- layer-2 MFMA GEMM + fused layer-3 products ----------------

__global__ __launch_bounds__(256) void gemm_l2_mfma(const unsigned short* __restrict__ Ab,
                                                    const unsigned short* __restrict__ Hb,
                                                    const unsigned short* __restrict__ Wt,
                                                    const float* __restrict__ bias,
                                                    const unsigned short* __restrict__ W3c,
                                                    unsigned short* __restrict__ g3b,
                                                    float* __restrict__ p3, int M) {
    constexpr int BM = 128, BK = 64;
    __shared__ unsigned short smem[26112];
#define SA(r, c) smem[(r) * 72 + (c)]
#define SB(r, c) smem[9216 + (r) * 72 + (c)]
#define SH(r, c) smem[(r) * 136 + (c)]
#define SW3(r, c) smem[17408 + (r) * 136 + (c)]

    const int tid = threadIdx.x;
    const int m0 = blockIdx.x * BM;
    const int lane = tid & 63;
    const int wid = tid >> 6;
    const int l15 = lane & 15;
    const int quad = lane >> 4;
    const int wm = (wid >> 1) * 64;
    const int wn = (wid & 1) * 64;

    f32x4 acc[4][4];
#pragma unroll
    for (int i = 0; i < 4; ++i)
#pragma unroll
        for (int j = 0; j < 4; ++j) acc[i][j] = (f32x4){0.f, 0.f, 0.f, 0.f};

    for (int k0 = 0; k0 < 256; k0 += BK) {
        const uint4* __restrict__ srcA = (const uint4*)((k0 < 128) ? Ab : Hb);
        const int kc = (k0 & 64) >> 3;
#pragma unroll
        for (int l = 0; l < 4; ++l) {
            int idx = tid + l * 256;
            int row = idx >> 3;
            int c8 = idx & 7;
            int gr = min(m0 + row, M - 1);
            uint4 va = srcA[(size_t)gr * 16 + kc + c8];
            *(uint4*)&SA(row, c8 * 8) = va;
            uint4 vb = ((const uint4*)Wt)[(size_t)row * 32 + (k0 >> 3) + c8];
            *(uint4*)&SB(row, c8 * 8) = vb;
        }
        __syncthreads();

#pragma unroll
        for (int ks = 0; ks < BK; ks += 32) {
            bf16x8 a[4], b[4];
#pragma unroll
            for (int t = 0; t < 4; ++t) {
                a[t] = *(const bf16x8*)&SA(wm + t * 16 + l15, ks + quad * 8);
                b[t] = *(const bf16x8*)&SB(wn + t * 16 + l15, ks + quad * 8);
            }
#pragma unroll
            for (int i = 0; i < 4; ++i)
#pragma unroll
                for (int j = 0; j < 4; ++j)
                    acc[i][j] = __builtin_amdgcn_mfma_f32_16x16x32_bf16(
                        a[i], b[j], acc[i][j], 0, 0, 0);
        }
        __syncthreads();
    }

#pragma unroll
    for (int j = 0; j < 4; ++j) {
        int n = wn + j * 16 + l15;
        float bv = bias[n];
#pragma unroll
        for (int i = 0; i < 4; ++i) {
#pragma unroll
            for (int r = 0; r < 4; ++r) {
                int ml = wm + i * 16 + quad * 4 + r;
                SH(ml, n) = f2bf_rne(fmaxf(acc[i][j][r] + bv, 0.f));
            }
        }
    }
#pragma unroll
    for (int l = 0; l < 4; ++l) {
        int idx = tid + l * 256;
        int row = idx >> 4;
        int c8 = idx & 15;
        uint4 v = ((const uint4*)W3c)[(size_t)row * 16 + c8];
        *(uint4*)&SW3(row, c8 * 8) = v;
    }
    __syncthreads();

    f32x4 acc2[2][4];
#pragma unroll
    for (int i = 0; i < 2; ++i)
#pragma unroll
        for (int j = 0; j < 4; ++j) acc2[i][j] = (f32x4){0.f, 0.f, 0.f, 0.f};

#pragma unroll
    for (int ks = 0; ks < 128; ks += 32) {
        bf16x8 a[2], b[4];
#pragma unroll
        for (int i = 0; i < 2; ++i)
            a[i] = *(const bf16x8*)&SH(wid * 32 + i * 16 + l15, ks + quad * 8);
#pragma unroll
        for (int j = 0; j < 4; ++j)
            b[j] = *(const bf16x8*)&SW3(j * 16 + l15, ks + quad * 8);
#pragma unroll
        for (int i = 0; i < 2; ++i)
#pragma unroll
            for (int j = 0; j < 4; ++j)
                acc2[i][j] = __builtin_amdgcn_mfma_f32_16x16x32_bf16(
                    a[i], b[j], acc2[i][j], 0, 0, 0);
    }

#pragma unroll
    for (int i = 0; i < 2; ++i) {
#pragma unroll
        for (int r = 0; r < 4; ++r) {
            int m = m0 + wid * 32 + i * 16 + quad * 4 + r;
            if (m >= M) continue;
#pragma unroll
            for (int j = 0; j < 4; ++j) {
                float v = acc2[i][j][r];
                if (j < 2) g3b[(size_t)m * 32 + j * 16 + l15] = f2bf_rne(v);
                else       p3[(size_t)m * 32 + (j - 2) * 16 + l15] = v;
            }
        }
    }
#undef SA
#undef SB
#undef SH
#undef SW3
}

// ---------------- fused combine + next-layer products (layers 3->4, 4->5) ----
// h = relu(agg + p + bias) (128x32 tile, bf16 in LDS, never global);
// [g_next | p_next] = h @ Wc^T  (Wc 64x32 bf16, one MFMA K-step).

__global__ __launch_bounds__(256) void combine_mfma(const float* __restrict__ agg,
                                                    const float* __restrict__ p,
                                                    const float* __restrict__ bias,
                                                    const unsigned short* __restrict__ Wc,
                                                    unsigned short* __restrict__ gb,
                                                    float* __restrict__ pnext, int M) {
    __shared__ unsigned short sH[128][40];
    __shared__ unsigned short sW[64][40];

    const int tid = threadIdx.x;
    const int m0 = blockIdx.x * 128;
    const int lane = tid & 63;
    const int wid = tid >> 6;
    const int l15 = lane & 15;
    const int quad = lane >> 4;

    // phase 1: h tile -> LDS bf16
#pragma unroll
    for (int l = 0; l < 4; ++l) {
        int idx = tid + l * 256;          // 0..1023 over 128x8 float4s
        int row = idx >> 3;
        int c4 = idx & 7;
        int gr = min(m0 + row, M - 1);
        float4 a = *(const float4*)&agg[(size_t)gr * 32 + c4 * 4];
        float4 pv = *(const float4*)&p[(size_t)gr * 32 + c4 * 4];
        float4 bv = *(const float4*)&bias[c4 * 4];
        uint2 o;
        o.x = pack_bf(fmaxf(a.x + pv.x + bv.x, 0.f), fmaxf(a.y + pv.y + bv.y, 0.f));
        o.y = pack_bf(fmaxf(a.z + pv.z + bv.z, 0.f), fmaxf(a.w + pv.w + bv.w, 0.f));
        *(uint2*)&sH[row][c4 * 4] = o;
    }
#pragma unroll
    for (int l = 0; l < 2; ++l) {
        int idx = tid + l * 256;          // 0..511 over 64x8 uint2 chunks
        int row = idx >> 3;
        int c4 = idx & 7;
        uint2 v = ((const uint2*)Wc)[(size_t)row * 8 + c4];
        *(uint2*)&sW[row][c4 * 4] = v;
    }
    __syncthreads();

    // phase 2: wave w rows w*32..+31; 2 m-tiles x 4 n-tiles, K=32 single step
    f32x4 acc[2][4];
    bf16x8 a[2], b[4];
#pragma unroll
    for (int i = 0; i < 2; ++i)
        a[i] = *(const bf16x8*)&sH[wid * 32 + i * 16 + l15][quad * 8];
#pragma unroll
    for (int j = 0; j < 4; ++j)
        b[j] = *(const bf16x8*)&sW[j * 16 + l15][quad * 8];
#pragma unroll
    for (int i = 0; i < 2; ++i)
#pragma unroll
        for (int j = 0; j < 4; ++j)
            acc[i][j] = __builtin_amdgcn_mfma_f32_16x16x32_bf16(
                a[i], b[j], (f32x4){0.f, 0.f, 0.f, 0.f}, 0, 0, 0);

#pragma unroll
    for (int i = 0; i < 2; ++i) {
#pragma unroll
        for (int r = 0; r < 4; ++r) {
            int m = m0 + wid * 32 + i * 16 + quad * 4 + r;
            if (m >= M) continue;
#pragma unroll
            for (int j = 0; j < 4; ++j) {
                float v = acc[i][j][r];
                if (j < 2) gb[(size_t)m * 32 + j * 16 + l15] = f2bf_rne(v);
                else       pnext[(size_t)m * 32 + (j - 2) * 16 + l15] = v;
            }
        }
    }
}

// final: out = relu(agg5 + p5 + bl5) . W_out + b_out
__global__ __launch_bounds__(256) void final5(const float* __restrict__ agg,
                                              const float* __restrict__ p,
                                              const float* __restrict__ bias,
                                              const float* __restrict__ Wout,
                                              const float* __restrict__ bout,
                                              float* __restrict__ out, int nnodes) {
    int n = blockIdx.x * 256 + threadIdx.x;
    if (n >= nnodes) return;
    const float4* a4 = (const float4*)(agg + (size_t)n * 32);
    const float4* p4 = (const float4*)(p + (size_t)n * 32);
    float acc = bout[0];
#pragma unroll
    for (int k4 = 0; k4 < 8; ++k4) {
        float4 a = a4[k4];
        float4 pv = p4[k4];
        const float* bv = bias + k4 * 4;
        const float* w = Wout + k4 * 4;
        acc = fmaf(fmaxf(a.x + pv.x + bv[0], 0.f), w[0], acc);
        acc = fmaf(fmaxf(a.y + pv.y + bv[1], 0.f), w[1], acc);
        acc = fmaf(fmaxf(a.z + pv.z + bv[2], 0.f), w[2], acc);
        acc = fmaf(fmaxf(a.w + pv.w + bv[3], 0.f), w[3], acc);
    }
    out[n] = acc;
}

// layer-1 linear (Cin=2): contiguous bf16 out
__global__ __launch_bounds__(256) void sage_linear2(const float* __restrict__ agg,
                                                    const float* __restrict__ h,
                                                    const float* __restrict__ Wl,
                                                    const float* __restrict__ bl,
                                                    const float* __restrict__ Wr,
                                                    unsigned short* __restrict__ out_bf,
                                                    int nnodes) {
    constexpr int Cout = 128;
    int t = blockIdx.x * blockDim.x + threadIdx.x;
    if (t >= nnodes * Cout) return;
    int node = t / Cout;
    int c = t - node * Cout;
    float2 a = ((const float2*)agg)[node];
    float2 hh = ((const float2*)h)[node];
    float acc = bl[c];
    acc = fmaf(a.x, Wl[c], acc);
    acc = fmaf(a.y, Wl[Cout + c], acc);
    acc = fmaf(hh.x, Wr[c], acc);
    acc = fmaf(hh.y, Wr[Cout + c], acc);
    acc = fmaxf(acc, 0.f);
    out_bf[t] = f2bf_rne(acc);
}

// ---------------- launch ----------------

extern "C" void kernel_launch(void* const* d_in, const int* in_sizes, int n_in,
                              void* d_out, int out_size, void* d_ws, size_t ws_size,
                              hipStream_t stream) {
    const float* x      = (const float*)d_in[0];
    const int*   ei     = (const int*)d_in[1];
    const float* Wl1    = (const float*)d_in[3];
    const float* bl1    = (const float*)d_in[4];
    const float* Wr1    = (const float*)d_in[5];
    const float* Wl2    = (const float*)d_in[6];
    const float* bl2    = (const float*)d_in[7];
    const float* Wr2    = (const float*)d_in[8];
    const float* Wl3    = (const float*)d_in[9];
    const float* bl3    = (const float*)d_in[10];
    const float* Wr3    = (const float*)d_in[11];
    const float* Wl4    = (const float*)d_in[12];
    const float* bl4    = (const float*)d_in[13];
    const float* Wr4    = (const float*)d_in[14];
    const float* Wl5    = (const float*)d_in[15];
    const float* bl5    = (const float*)d_in[16];
    const float* Wr5    = (const float*)d_in[17];
    const float* W_out  = (const float*)d_in[18];
    const float* b_out  = (const float*)d_in[19];
    float* out = (float*)d_out;

    const int N = N_NODES, E = N_EDGES;
    const int* e_src = ei;
    const int* e_dst = ei + E;

    size_t off = 0;
    auto carve = [&](size_t bytes) {
        void* p = (char*)d_ws + off;
        off += (bytes + 255) & ~(size_t)255;
        return p;
    };
    int*   offsets  = (int*)carve((size_t)(N + 1) * 4);
    float* inv_deg  = (float*)carve((size_t)N * 4);
    int*   ssrc     = (int*)carve((size_t)E * 4);
    int*   blkCntT  = (int*)carve((size_t)NBUCK * NBUCK * 4);
    int*   blkBaseL = (int*)carve((size_t)NBUCK * NBUCK * 4);
    int*   bucketTotal = (int*)carve((size_t)NBUCK * 4);
    int*   bstart   = (int*)carve((size_t)(NBUCK + 1) * 4);
    int2*  staging  = (int2*)carve((size_t)E * 8);
    unsigned short* Wt  = (unsigned short*)carve((size_t)128 * 256 * 2);
    unsigned short* W3c = (unsigned short*)carve((size_t)64 * 128 * 2);
    unsigned short* W4c = (unsigned short*)carve((size_t)64 * 32 * 2);
    unsigned short* W5c = (unsigned short*)carve((size_t)64 * 32 * 2);
    float* agg      = (float*)carve((size_t)N * 128 * 4);   // 4x (N x 32) fp32 slots
    float* bufA     = (float*)carve((size_t)N * 128 * 4);   // 2x (N x 128) bf16
    unsigned short* g3b = (unsigned short*)carve((size_t)N * 32 * 2);
    unsigned short* g4b = (unsigned short*)carve((size_t)N * 32 * 2);
    unsigned short* g5b = (unsigned short*)carve((size_t)N * 32 * 2);

    float* slotA = agg;                       // p3 / p5
    float* slotB = agg + (size_t)N * 32;      // agg3 / agg5
    float* slotC = agg + (size_t)N * 64;      // p4 / layer-1 scratch
    float* slotD = agg + (size_t)N * 96;      // agg4
    unsigned short* h1_bf = (unsigned short*)bufA;
    unsigned short* aggB  = (unsigned short*)bufA + (size_t)N * 128;

    // --- CSR build: 256-bucket counting sort ---
    pa_count<<<NBUCK, 256, 0, stream>>>(e_dst, blkCntT);
    pa_scan1<<<NBUCK, 256, 0, stream>>>(blkCntT, blkBaseL, bucketTotal);
    pa_scan2<<<1, 256, 0, stream>>>(bucketTotal, bstart, offsets);
    pa_scatter<<<NBUCK, 256, 0, stream>>>(e_src, e_dst, blkCntT, blkBaseL, bstart, staging);
    pc_fill<<<NBUCK, 512, 0, stream>>>(staging, bstart, ssrc, offsets, inv_deg);
    prep_wt<<<128, 256, 0, stream>>>(Wl2, Wr2, Wt);
    prep_w3<<<32, 256, 0, stream>>>(Wl3, Wr3, W3c);
    prep_w32<<<8, 256, 0, stream>>>(Wl4, Wr4, W4c);
    prep_w32<<<8, 256, 0, stream>>>(Wl5, Wr5, W5c);

    const int gemm_grid = (N + 127) / 128;

    // --- layer 1: 2 -> 128 (bf16 out) ---
    aggregate2<<<(N + 255) / 256, 256, 0, stream>>>(x, offsets, ssrc, inv_deg, slotC, N);
    sage_linear2<<<(N * 128 + 255) / 256, 256, 0, stream>>>(slotC, x, Wl1, bl1, Wr1, h1_bf, N);

    // --- layer 2 + layer-3 products ---
    aggregate_bf128<<<(N * 16 + 255) / 256, 256, 0, stream>>>(h1_bf, offsets, ssrc,
                                                              inv_deg, aggB, N);
    gemm_l2_mfma<<<gemm_grid, 256, 0, stream>>>(aggB, h1_bf, Wt, bl2, W3c, g3b, slotA, N);

    // --- layer 3 finish + layer-4 products ---
    aggregate_bf32<<<(N * 4 + 255) / 256, 256, 0, stream>>>(g3b, offsets, ssrc, inv_deg, slotB, N);
    combine_mfma<<<gemm_grid, 256, 0, stream>>>(slotB, slotA, bl3, W4c, g4b, slotC, N);

    // --- layer 4 finish + layer-5 products ---
    aggregate_bf32<<<(N * 4 + 255) / 256, 256, 0, stream>>>(g4b, offsets, ssrc, inv_deg, slotD, N);
    combine_mfma<<<gemm_grid, 256, 0, stream>>>(slotD, slotC, bl4, W5c, g5b, slotA, N);

    // --- layer 5 finish + output projection ---
    aggregate_bf32<<<(N * 4 + 255) / 256, 256, 0, stream>>>(g5b, offsets, ssrc, inv_deg, slotB, N);
    final5<<<(N + 255) / 256, 256, 0, stream>>>(slotB, slotA, bl5, W_out, b_out, out, N);
}

// Round 17
// 341.906 us; speedup vs baseline: 1.2870x; 1.0893x over previous
//
#include <hip/hip_runtime.h>
#include <hip/hip_bf16.h>

#define N_NODES 100000
#define N_EDGES 1600000
#define NBUCK 256
#define NODES_PER_BUCKET 391        // 256*391 = 100096 >= 100000
#define EDGES_PER_CHUNK (N_EDGES / NBUCK)   // 6250 exactly
#define FILL_LDS_CAP 8192           // mean 6250, sigma~79 -> +24 sigma

typedef __bf16 bf16x8 __attribute__((ext_vector_type(8)));
typedef float f32x4 __attribute__((ext_vector_type(4)));

// ---------------- helpers ----------------

__device__ inline unsigned short f2bf_rne(float v) {
    unsigned u = __float_as_uint(v);
    u += 0x7fffu + ((u >> 16) & 1u);
    return (unsigned short)(u >> 16);
}

__device__ inline unsigned pack_bf(float a, float b) {
    return (unsigned)f2bf_rne(a) | ((unsigned)f2bf_rne(b) << 16);
}

__device__ inline void acc8_bf(float* a, uint4 p) {
    a[0] += __uint_as_float(p.x << 16);
    a[1] += __uint_as_float(p.x & 0xffff0000u);
    a[2] += __uint_as_float(p.y << 16);
    a[3] += __uint_as_float(p.y & 0xffff0000u);
    a[4] += __uint_as_float(p.z << 16);
    a[5] += __uint_as_float(p.z & 0xffff0000u);
    a[6] += __uint_as_float(p.w << 16);
    a[7] += __uint_as_float(p.w & 0xffff0000u);
}

// ---------------- CSR build: 256-bucket counting sort ----------------

__global__ __launch_bounds__(256) void pa_count(const int* __restrict__ dst,
                                                int* __restrict__ blkCntT) {
    __shared__ int hist[NBUCK];
    hist[threadIdx.x] = 0;
    __syncthreads();
    int b0 = blockIdx.x * EDGES_PER_CHUNK;
    int b1 = min(b0 + EDGES_PER_CHUNK, N_EDGES);
    for (int i = b0 + (int)threadIdx.x; i < b1; i += 256) {
        int d = __builtin_nontemporal_load(&dst[i]);
        atomicAdd(&hist[d / NODES_PER_BUCKET], 1);
    }
    __syncthreads();
    blkCntT[threadIdx.x * NBUCK + blockIdx.x] = hist[threadIdx.x];
}

__global__ __launch_bounds__(256) void pa_scan1(const int* __restrict__ blkCntT,
                                                int* __restrict__ blkBaseL,
                                                int* __restrict__ bucketTotal) {
    __shared__ int s[256];
    int t = threadIdx.x;
    int v = blkCntT[blockIdx.x * NBUCK + t];
    s[t] = v;
    __syncthreads();
    for (int off = 1; off < 256; off <<= 1) {
        int u = (t >= off) ? s[t - off] : 0;
        __syncthreads();
        s[t] += u;
        __syncthreads();
    }
    blkBaseL[blockIdx.x * NBUCK + t] = s[t] - v;
    if (t == 255) bucketTotal[blockIdx.x] = s[255];
}

__global__ __launch_bounds__(256) void pa_scan2(const int* __restrict__ bucketTotal,
                                                int* __restrict__ bstart,
                                                int* __restrict__ offsets) {
    __shared__ int s[256];
    int t = threadIdx.x;
    int v = bucketTotal[t];
    s[t] = v;
    __syncthreads();
    for (int off = 1; off < 256; off <<= 1) {
        int u = (t >= off) ? s[t - off] : 0;
        __syncthreads();
        s[t] += u;
        __syncthreads();
    }
    bstart[t] = s[t] - v;
    if (t == 255) {
        bstart[256] = s[255];
        offsets[N_NODES] = s[255];
    }
}

__global__ __launch_bounds__(256) void pa_scatter(const int* __restrict__ src,
                                                  const int* __restrict__ dst,
                                                  const int* __restrict__ blkCntT,
                                                  const int* __restrict__ blkBaseL,
                                                  const int* __restrict__ bstart,
                                                  int2* __restrict__ staging) {
    __shared__ int runStart[NBUCK];
    __shared__ int cur[NBUCK];
    __shared__ int gbase[NBUCK];
    __shared__ int2 buf[EDGES_PER_CHUNK];

    const int tid = threadIdx.x;
    const int g = blockIdx.x;
    const int b0 = g * EDGES_PER_CHUNK;
    const int b1 = min(b0 + EDGES_PER_CHUNK, N_EDGES);

    {
        __shared__ int s[256];
        int v = blkCntT[tid * NBUCK + g];
        s[tid] = v;
        __syncthreads();
        for (int off = 1; off < 256; off <<= 1) {
            int u = (tid >= off) ? s[tid - off] : 0;
            __syncthreads();
            s[tid] += u;
            __syncthreads();
        }
        runStart[tid] = s[tid] - v;
        cur[tid] = s[tid] - v;
        gbase[tid] = bstart[tid] + blkBaseL[tid * NBUCK + g];
    }
    __syncthreads();
    for (int i = b0 + tid; i < b1; i += 256) {
        int d = __builtin_nontemporal_load(&dst[i]);
        int s_ = __builtin_nontemporal_load(&src[i]);
        int k = d / NODES_PER_BUCKET;
        int p = atomicAdd(&cur[k], 1);
        buf[p] = make_int2(s_, d);
    }
    __syncthreads();
    int cnt = b1 - b0;
    for (int i = tid; i < cnt; i += 256) {
        int2 e = buf[i];
        int k = e.y / NODES_PER_BUCKET;
        staging[gbase[k] + (i - runStart[k])] = e;
    }
}

__global__ __launch_bounds__(512) void pc_fill(const int2* __restrict__ staging,
                                               const int* __restrict__ bstart,
                                               int* __restrict__ ssrc,
                                               int* __restrict__ offsets,
                                               float* __restrict__ inv_deg) {
    __shared__ int scnt[NODES_PER_BUCKET];
    __shared__ int sexc[NODES_PER_BUCKET];
    __shared__ int scur[NODES_PER_BUCKET];
    __shared__ int ssrcL[FILL_LDS_CAP];

    const int tid = threadIdx.x;
    const int b = blockIdx.x;
    const int node0 = b * NODES_PER_BUCKET;
    const int nn = min(node0 + NODES_PER_BUCKET, N_NODES) - node0;
    if (nn <= 0) return;
    const int es = bstart[b], ee = bstart[b + 1];
    const int cnt = ee - es;

    for (int j = tid; j < nn; j += 512) scnt[j] = 0;
    __syncthreads();
    for (int i = es + tid; i < ee; i += 512) {
        int2 e = staging[i];
        atomicAdd(&scnt[e.y - node0], 1);
    }
    __syncthreads();

    if (tid < 64) {
        int base = tid * 7;
        int vals[7];
        int run = 0;
#pragma unroll
        for (int j = 0; j < 7; ++j) {
            int idx = base + j;
            int c = (idx < nn) ? scnt[idx] : 0;
            vals[j] = run;
            run += c;
        }
        int inc = run;
#pragma unroll
        for (int off = 1; off < 64; off <<= 1) {
            int u = __shfl_up(inc, off, 64);
            if (tid >= off) inc += u;
        }
        int laneExcl = inc - run;
#pragma unroll
        for (int j = 0; j < 7; ++j) {
            int idx = base + j;
            if (idx < nn) sexc[idx] = laneExcl + vals[j];
        }
    }
    __syncthreads();

    for (int j = tid; j < nn; j += 512) {
        int c = scnt[j];
        int ex = sexc[j];
        offsets[node0 + j] = es + ex;
        inv_deg[node0 + j] = 1.0f / (float)max(c, 1);
        scur[j] = ex;
    }
    __syncthreads();

    if (cnt <= FILL_LDS_CAP) {
        for (int i = es + tid; i < ee; i += 512) {
            int2 e = staging[i];
            int p = atomicAdd(&scur[e.y - node0], 1);
            ssrcL[p] = e.x;
        }
        __syncthreads();
        for (int i = tid; i < cnt; i += 512) ssrc[es + i] = ssrcL[i];
    } else {
        for (int i = es + tid; i < ee; i += 512) {
            int2 e = staging[i];
            int p = atomicAdd(&scur[e.y - node0], 1);
            ssrc[es + p] = e.x;
        }
    }
}

// ---------------- aggregation ----------------

__global__ __launch_bounds__(256) void aggregate_bf128(const unsigned short* __restrict__ hb,
                                                       const int* __restrict__ offs,
                                                       const int* __restrict__ ssrc,
                                                       const float* __restrict__ inv_deg,
                                                       unsigned short* __restrict__ aggb,
                                                       int nnodes) {
    int t = blockIdx.x * 256 + threadIdx.x;
    if (t >= nnodes * 16) return;
    int node = t >> 4;
    int c = t & 15;
    int b = offs[node], e = offs[node + 1];
    const uint4* __restrict__ hb4 = (const uint4*)hb;
    float acc[8] = {0.f, 0.f, 0.f, 0.f, 0.f, 0.f, 0.f, 0.f};
    int i = b;
    for (; i + 4 <= e; i += 4) {
        uint4 p0 = hb4[(size_t)ssrc[i] * 16 + c];
        uint4 p1 = hb4[(size_t)ssrc[i + 1] * 16 + c];
        uint4 p2 = hb4[(size_t)ssrc[i + 2] * 16 + c];
        uint4 p3 = hb4[(size_t)ssrc[i + 3] * 16 + c];
        acc8_bf(acc, p0);
        acc8_bf(acc, p1);
        acc8_bf(acc, p2);
        acc8_bf(acc, p3);
    }
    for (; i < e; ++i) {
        uint4 p = hb4[(size_t)ssrc[i] * 16 + c];
        acc8_bf(acc, p);
    }
    float s = inv_deg[node];
    uint4 o;
    o.x = pack_bf(acc[0] * s, acc[1] * s);
    o.y = pack_bf(acc[2] * s, acc[3] * s);
    o.z = pack_bf(acc[4] * s, acc[5] * s);
    o.w = pack_bf(acc[6] * s, acc[7] * s);
    ((uint4*)aggb)[t] = o;
}

__global__ __launch_bounds__(256) void aggregate2(const float* __restrict__ h,
                                                  const int* __restrict__ offs,
                                                  const int* __restrict__ ssrc,
                                                  const float* __restrict__ inv_deg,
                                                  float* __restrict__ agg, int nnodes) {
    int node = blockIdx.x * blockDim.x + threadIdx.x;
    if (node >= nnodes) return;
    int b = offs[node], e = offs[node + 1];
    const float2* __restrict__ h2 = (const float2*)h;
    float2 a0 = make_float2(0.f, 0.f), a1 = make_float2(0.f, 0.f);
    int i = b;
    for (; i + 2 <= e; i += 2) {
        float2 v = h2[ssrc[i]];
        float2 w = h2[ssrc[i + 1]];
        a0.x += v.x; a0.y += v.y;
        a1.x += w.x; a1.y += w.y;
    }
    if (i < e) {
        float2 v = h2[ssrc[i]];
        a0.x += v.x; a0.y += v.y;
    }
    float s = inv_deg[node];
    ((float2*)agg)[node] = make_float2((a0.x + a1.x) * s, (a0.y + a1.y) * s);
}

// ---------------- weight prep (single dispatch) ----------------
// Wt: 128x256 (k=[Wl2;Wr2], transposed), W3c: 64x128, W4c/W5c: 64x32.

__global__ __launch_bounds__(256) void prep_all(const float* __restrict__ Wl2,
                                                const float* __restrict__ Wr2,
                                                const float* __restrict__ Wl3,
                                                const float* __restrict__ Wr3,
                                                const float* __restrict__ Wl4,
                                                const float* __restrict__ Wr4,
                                                const float* __restrict__ Wl5,
                                                const float* __restrict__ Wr5,
                                                unsigned short* __restrict__ Wt,
                                                unsigned short* __restrict__ W3c,
                                                unsigned short* __restrict__ W4c,
                                                unsigned short* __restrict__ W5c) {
    int idx = blockIdx.x * 256 + threadIdx.x;
    if (idx < 32768) {
        int n = idx >> 8, k = idx & 255;
        float v = (k < 128) ? Wl2[k * 128 + n] : Wr2[(k - 128) * 128 + n];
        Wt[idx] = f2bf_rne(v);
    } else if (idx < 32768 + 8192) {
        int j = idx - 32768;
        int n = j >> 7, k = j & 127;
        float v = (n < 32) ? Wl3[k * 32 + n] : Wr3[k * 32 + (n - 32)];
        W3c[j] = f2bf_rne(v);
    } else if (idx < 32768 + 8192 + 2048) {
        int j = idx - 32768 - 8192;
        int n = j >> 5, k = j & 31;
        float v = (n < 32) ? Wl4[k * 32 + n] : Wr4[k * 32 + (n - 32)];
        W4c[j] = f2bf_rne(v);
    } else if (idx < 32768 + 8192 + 4096) {
        int j = idx - 32768 - 8192 - 2048;
        int n = j >> 5, k = j & 31;
        float v = (n < 32) ? Wl5[k * 32 + n] : Wr5[k * 32 + (n - 32)];
        W5c[j] = f2bf_rne(v);
    }
}

// ---------------- layer-2 MFMA GEMM + fused layer-3 products ----------------

__global__ __launch_bounds__(256) void gemm_l2_mfma(const unsigned short* __restrict__ Ab,
                                                    const unsigned short* __restrict__ Hb,
                                                    const unsigned short* __restrict__ Wt,
                                                    const float* __restrict__ bias,
                                                    const unsigned short* __restrict__ W3c,
                                                    unsigned short* __restrict__ g3b,
                                                    float* __restrict__ p3, int M) {
    constexpr int BM = 128, BK = 64;
    __shared__ unsigned short smem[26112];
#define SA(r, c) smem[(r) * 72 + (c)]
#define SB(r, c) smem[9216 + (r) * 72 + (c)]
#define SH(r, c) smem[(r) * 136 + (c)]
#define SW3(r, c) smem[17408 + (r) * 136 + (c)]

    const int tid = threadIdx.x;
    const int m0 = blockIdx.x * BM;
    const int lane = tid & 63;
    const int wid = tid >> 6;
    const int l15 = lane & 15;
    const int quad = lane >> 4;
    const int wm = (wid >> 1) * 64;
    const int wn = (wid & 1) * 64;

    f32x4 acc[4][4];
#pragma unroll
    for (int i = 0; i < 4; ++i)
#pragma unroll
        for (int j = 0; j < 4; ++j) acc[i][j] = (f32x4){0.f, 0.f, 0.f, 0.f};

    for (int k0 = 0; k0 < 256; k0 += BK) {
        const uint4* __restrict__ srcA = (const uint4*)((k0 < 128) ? Ab : Hb);
        const int kc = (k0 & 64) >> 3;
#pragma unroll
        for (int l = 0; l < 4; ++l) {
            int idx = tid + l * 256;
            int row = idx >> 3;
            int c8 = idx & 7;
            int gr = min(m0 + row, M - 1);
            uint4 va = srcA[(size_t)gr * 16 + kc + c8];
            *(uint4*)&SA(row, c8 * 8) = va;
            uint4 vb = ((const uint4*)Wt)[(size_t)row * 32 + (k0 >> 3) + c8];
            *(uint4*)&SB(row, c8 * 8) = vb;
        }
        __syncthreads();

#pragma unroll
        for (int ks = 0; ks < BK; ks += 32) {
            bf16x8 a[4], b[4];
#pragma unroll
            for (int t = 0; t < 4; ++t) {
                a[t] = *(const bf16x8*)&SA(wm + t * 16 + l15, ks + quad * 8);
                b[t] = *(const bf16x8*)&SB(wn + t * 16 + l15, ks + quad * 8);
            }
#pragma unroll
            for (int i = 0; i < 4; ++i)
#pragma unroll
                for (int j = 0; j < 4; ++j)
                    acc[i][j] = __builtin_amdgcn_mfma_f32_16x16x32_bf16(
                        a[i], b[j], acc[i][j], 0, 0, 0);
        }
        __syncthreads();
    }

#pragma unroll
    for (int j = 0; j < 4; ++j) {
        int n = wn + j * 16 + l15;
        float bv = bias[n];
#pragma unroll
        for (int i = 0; i < 4; ++i) {
#pragma unroll
            for (int r = 0; r < 4; ++r) {
                int ml = wm + i * 16 + quad * 4 + r;
                SH(ml, n) = f2bf_rne(fmaxf(acc[i][j][r] + bv, 0.f));
            }
        }
    }
#pragma unroll
    for (int l = 0; l < 4; ++l) {
        int idx = tid + l * 256;
        int row = idx >> 4;
        int c8 = idx & 15;
        uint4 v = ((const uint4*)W3c)[(size_t)row * 16 + c8];
        *(uint4*)&SW3(row, c8 * 8) = v;
    }
    __syncthreads();

    f32x4 acc2[2][4];
#pragma unroll
    for (int i = 0; i < 2; ++i)
#pragma unroll
        for (int j = 0; j < 4; ++j) acc2[i][j] = (f32x4){0.f, 0.f, 0.f, 0.f};

#pragma unroll
    for (int ks = 0; ks < 128; ks += 32) {
        bf16x8 a[2], b[4];
#pragma unroll
        for (int i = 0; i < 2; ++i)
            a[i] = *(const bf16x8*)&SH(wid * 32 + i * 16 + l15, ks + quad * 8);
#pragma unroll
        for (int j = 0; j < 4; ++j)
            b[j] = *(const bf16x8*)&SW3(j * 16 + l15, ks + quad * 8);
#pragma unroll
        for (int i = 0; i < 2; ++i)
#pragma unroll
            for (int j = 0; j < 4; ++j)
                acc2[i][j] = __builtin_amdgcn_mfma_f32_16x16x32_bf16(
                    a[i], b[j], acc2[i][j], 0, 0, 0);
    }

#pragma unroll
    for (int i = 0; i < 2; ++i) {
#pragma unroll
        for (int r = 0; r < 4; ++r) {
            int m = m0 + wid * 32 + i * 16 + quad * 4 + r;
            if (m >= M) continue;
#pragma unroll
            for (int j = 0; j < 4; ++j) {
                float v = acc2[i][j][r];
                if (j < 2) g3b[(size_t)m * 32 + j * 16 + l15] = f2bf_rne(v);
                else       p3[(size_t)m * 32 + (j - 2) * 16 + l15] = v;
            }
        }
    }
#undef SA
#undef SB
#undef SH
#undef SW3
}

// ---------------- fused gather + combine + next-layer products --------------
// Per block: 64 nodes (4 threads/node). Gather g_prev (bf16, 32-wide), then
// h = relu(agg + p + bias) -> LDS bf16 tile; 4 MFMAs/wave vs Wc (64x32)
// give [g_next | p_next]. The fp32 agg intermediate never hits global.

__global__ __launch_bounds__(256) void aggregate_combine32(
        const unsigned short* __restrict__ gb_prev,
        const int* __restrict__ offs,
        const int* __restrict__ ssrc,
        const float* __restrict__ inv_deg,
        const float* __restrict__ p,
        const float* __restrict__ bias,
        const unsigned short* __restrict__ Wc,   // 64 x 32 bf16
        unsigned short* __restrict__ g_next,
        float* __restrict__ p_next, int nnodes) {
    __shared__ unsigned short hB[64][40];
    __shared__ unsigned short wB[64][40];

    const int tid = threadIdx.x;
    const int node0 = blockIdx.x * 64;
    const int node = node0 + (tid >> 2);
    const int c = tid & 3;
    const int ln = tid >> 2;

    // stage Wc (64 rows x 8 uint2 chunks)
#pragma unroll
    for (int l = 0; l < 2; ++l) {
        int id = tid + l * 256;
        int r = id >> 3, cc = id & 7;
        uint2 v = ((const uint2*)Wc)[(size_t)r * 8 + cc];
        *(uint2*)&wB[r][cc * 4] = v;
    }

    uint4 hout = make_uint4(0u, 0u, 0u, 0u);
    if (node < nnodes) {
        int b = offs[node], e = offs[node + 1];
        const uint4* __restrict__ hb4 = (const uint4*)gb_prev;
        float acc[8] = {0.f, 0.f, 0.f, 0.f, 0.f, 0.f, 0.f, 0.f};
        int i = b;
        for (; i + 4 <= e; i += 4) {
            uint4 p0 = hb4[(size_t)ssrc[i] * 4 + c];
            uint4 p1 = hb4[(size_t)ssrc[i + 1] * 4 + c];
            uint4 p2 = hb4[(size_t)ssrc[i + 2] * 4 + c];
            uint4 p3 = hb4[(size_t)ssrc[i + 3] * 4 + c];
            acc8_bf(acc, p0);
            acc8_bf(acc, p1);
            acc8_bf(acc, p2);
            acc8_bf(acc, p3);
        }
        for (; i < e; ++i) acc8_bf(acc, hb4[(size_t)ssrc[i] * 4 + c]);
        float s = inv_deg[node];
        const float4* prow = (const float4*)(p + (size_t)node * 32 + c * 8);
        float4 p0 = prow[0], p1 = prow[1];
        const float* bb = bias + c * 8;
        float h0 = fmaxf(acc[0] * s + p0.x + bb[0], 0.f);
        float h1 = fmaxf(acc[1] * s + p0.y + bb[1], 0.f);
        float h2 = fmaxf(acc[2] * s + p0.z + bb[2], 0.f);
        float h3 = fmaxf(acc[3] * s + p0.w + bb[3], 0.f);
        float h4 = fmaxf(acc[4] * s + p1.x + bb[4], 0.f);
        float h5 = fmaxf(acc[5] * s + p1.y + bb[5], 0.f);
        float h6 = fmaxf(acc[6] * s + p1.z + bb[6], 0.f);
        float h7 = fmaxf(acc[7] * s + p1.w + bb[7], 0.f);
        hout.x = pack_bf(h0, h1);
        hout.y = pack_bf(h2, h3);
        hout.z = pack_bf(h4, h5);
        hout.w = pack_bf(h6, h7);
    }
    *(uint4*)&hB[ln][c * 8] = hout;    // zeros for invalid rows
    __syncthreads();

    // MFMA: wave w handles local nodes w*16..+15; outputs n = j*16+l15
    const int lane = tid & 63;
    const int wid = tid >> 6;
    const int l15 = lane & 15;
    const int quad = lane >> 4;

    bf16x8 a = *(const bf16x8*)&hB[wid * 16 + l15][quad * 8];
    f32x4 accm[4];
#pragma unroll
    for (int j = 0; j < 4; ++j) {
        bf16x8 b = *(const bf16x8*)&wB[j * 16 + l15][quad * 8];
        accm[j] = __builtin_amdgcn_mfma_f32_16x16x32_bf16(
            a, b, (f32x4){0.f, 0.f, 0.f, 0.f}, 0, 0, 0);
    }

#pragma unroll
    for (int r = 0; r < 4; ++r) {
        int m = node0 + wid * 16 + quad * 4 + r;
        if (m >= nnodes) continue;
#pragma unroll
        for (int j = 0; j < 4; ++j) {
            float v = accm[j][r];
            if (j < 2) g_next[(size_t)m * 32 + j * 16 + l15] = f2bf_rne(v);
            else       p_next[(size_t)m * 32 + (j - 2) * 16 + l15] = v;
        }
    }
}

// fused gather + layer-5 finish + output projection
__global__ __launch_bounds__(256) void aggregate_final32(
        const unsigned short* __restrict__ gb_prev,
        const int* __restrict__ offs,
        const int* __restrict__ ssrc,
        const float* __restrict__ inv_deg,
        const float* __restrict__ p,
        const float* __restrict__ bias,
        const float* __restrict__ Wout,
        const float* __restrict__ bout,
        float* __restrict__ out, int nnodes) {
    int t = blockIdx.x * 256 + threadIdx.x;
    int node = t >> 2;
    int c = t & 3;
    if (node >= nnodes) return;
    int b = offs[node], e = offs[node + 1];
    const uint4* __restrict__ hb4 = (const uint4*)gb_prev;
    float acc[8] = {0.f, 0.f, 0.f, 0.f, 0.f, 0.f, 0.f, 0.f};
    int i = b;
    for (; i + 4 <= e; i += 4) {
        uint4 p0 = hb4[(size_t)ssrc[i] * 4 + c];
        uint4 p1 = hb4[(size_t)ssrc[i + 1] * 4 + c];
        uint4 p2 = hb4[(size_t)ssrc[i + 2] * 4 + c];
        uint4 p3 = hb4[(size_t)ssrc[i + 3] * 4 + c];
        acc8_bf(acc, p0);
        acc8_bf(acc, p1);
        acc8_bf(acc, p2);
        acc8_bf(acc, p3);
    }
    for (; i < e; ++i) acc8_bf(acc, hb4[(size_t)ssrc[i] * 4 + c]);
    float s = inv_deg[node];
    const float4* prow = (const float4*)(p + (size_t)node * 32 + c * 8);
    float4 p0 = prow[0], p1 = prow[1];
    const float* bb = bias + c * 8;
    const float* w = Wout + c * 8;
    float sum = 0.f;
    sum = fmaf(fmaxf(acc[0] * s + p0.x + bb[0], 0.f), w[0], sum);
    sum = fmaf(fmaxf(acc[1] * s + p0.y + bb[1], 0.f), w[1], sum);
    sum = fmaf(fmaxf(acc[2] * s + p0.z + bb[2], 0.f), w[2], sum);
    sum = fmaf(fmaxf(acc[3] * s + p0.w + bb[3], 0.f), w[3], sum);
    sum = fmaf(fmaxf(acc[4] * s + p1.x + bb[4], 0.f), w[4], sum);
    sum = fmaf(fmaxf(acc[5] * s + p1.y + bb[5], 0.f), w[5], sum);
    sum = fmaf(fmaxf(acc[6] * s + p1.z + bb[6], 0.f), w[6], sum);
    sum = fmaf(fmaxf(acc[7] * s + p1.w + bb[7], 0.f), w[7], sum);
    sum += __shfl_down(sum, 2, 4);
    sum += __shfl_down(sum, 1, 4);
    if (c == 0) out[node] = sum + bout[0];
}

// layer-1 linear (Cin=2): contiguous bf16 out
__global__ __launch_bounds__(256) void sage_linear2(const float* __restrict__ agg,
                                                    const float* __restrict__ h,
                                                    const float* __restrict__ Wl,
                                                    const float* __restrict__ bl,
                                                    const float* __restrict__ Wr,
                                                    unsigned short* __restrict__ out_bf,
                                                    int nnodes) {
    constexpr int Cout = 128;
    int t = blockIdx.x * blockDim.x + threadIdx.x;
    if (t >= nnodes * Cout) return;
    int node = t / Cout;
    int c = t - node * Cout;
    float2 a = ((const float2*)agg)[node];
    float2 hh = ((const float2*)h)[node];
    float acc = bl[c];
    acc = fmaf(a.x, Wl[c], acc);
    acc = fmaf(a.y, Wl[Cout + c], acc);
    acc = fmaf(hh.x, Wr[c], acc);
    acc = fmaf(hh.y, Wr[Cout + c], acc);
    acc = fmaxf(acc, 0.f);
    out_bf[t] = f2bf_rne(acc);
}

// ---------------- launch ----------------

extern "C" void kernel_launch(void* const* d_in, const int* in_sizes, int n_in,
                              void* d_out, int out_size, void* d_ws, size_t ws_size,
                              hipStream_t stream) {
    const float* x      = (const float*)d_in[0];
    const int*   ei     = (const int*)d_in[1];
    const float* Wl1    = (const float*)d_in[3];
    const float* bl1    = (const float*)d_in[4];
    const float* Wr1    = (const float*)d_in[5];
    const float* Wl2    = (const float*)d_in[6];
    const float* bl2    = (const float*)d_in[7];
    const float* Wr2    = (const float*)d_in[8];
    const float* Wl3    = (const float*)d_in[9];
    const float* bl3    = (const float*)d_in[10];
    const float* Wr3    = (const float*)d_in[11];
    const float* Wl4    = (const float*)d_in[12];
    const float* bl4    = (const float*)d_in[13];
    const float* Wr4    = (const float*)d_in[14];
    const float* Wl5    = (const float*)d_in[15];
    const float* bl5    = (const float*)d_in[16];
    const float* Wr5    = (const float*)d_in[17];
    const float* W_out  = (const float*)d_in[18];
    const float* b_out  = (const float*)d_in[19];
    float* out = (float*)d_out;

    const int N = N_NODES, E = N_EDGES;
    const int* e_src = ei;
    const int* e_dst = ei + E;

    size_t off = 0;
    auto carve = [&](size_t bytes) {
        void* p = (char*)d_ws + off;
        off += (bytes + 255) & ~(size_t)255;
        return p;
    };
    int*   offsets  = (int*)carve((size_t)(N + 1) * 4);
    float* inv_deg  = (float*)carve((size_t)N * 4);
    int*   ssrc     = (int*)carve((size_t)E * 4);
    int*   blkCntT  = (int*)carve((size_t)NBUCK * NBUCK * 4);
    int*   blkBaseL = (int*)carve((size_t)NBUCK * NBUCK * 4);
    int*   bucketTotal = (int*)carve((size_t)NBUCK * 4);
    int*   bstart   = (int*)carve((size_t)(NBUCK + 1) * 4);
    int2*  staging  = (int2*)carve((size_t)E * 8);
    unsigned short* Wt  = (unsigned short*)carve((size_t)128 * 256 * 2);
    unsigned short* W3c = (unsigned short*)carve((size_t)64 * 128 * 2);
    unsigned short* W4c = (unsigned short*)carve((size_t)64 * 32 * 2);
    unsigned short* W5c = (unsigned short*)carve((size_t)64 * 32 * 2);
    float* agg      = (float*)carve((size_t)N * 128 * 4);
    float* bufA     = (float*)carve((size_t)N * 128 * 4);
    unsigned short* g3b = (unsigned short*)carve((size_t)N * 32 * 2);
    unsigned short* g4b = (unsigned short*)carve((size_t)N * 32 * 2);
    unsigned short* g5b = (unsigned short*)carve((size_t)N * 32 * 2);

    float* slotA = agg;                       // p3 / p5
    float* slotC = agg + (size_t)N * 64;      // p4 / layer-1 scratch
    unsigned short* h1_bf = (unsigned short*)bufA;
    unsigned short* aggB  = (unsigned short*)bufA + (size_t)N * 128;

    // --- CSR build ---
    pa_count<<<NBUCK, 256, 0, stream>>>(e_dst, blkCntT);
    pa_scan1<<<NBUCK, 256, 0, stream>>>(blkCntT, blkBaseL, bucketTotal);
    pa_scan2<<<1, 256, 0, stream>>>(bucketTotal, bstart, offsets);
    pa_scatter<<<NBUCK, 256, 0, stream>>>(e_src, e_dst, blkCntT, blkBaseL, bstart, staging);
    pc_fill<<<NBUCK, 512, 0, stream>>>(staging, bstart, ssrc, offsets, inv_deg);
    prep_all<<<176, 256, 0, stream>>>(Wl2, Wr2, Wl3, Wr3, Wl4, Wr4, Wl5, Wr5,
                                      Wt, W3c, W4c, W5c);

    const int gemm_grid = (N + 127) / 128;
    const int comb_grid = (N + 63) / 64;

    // --- layer 1: 2 -> 128 (bf16 out) ---
    aggregate2<<<(N + 255) / 256, 256, 0, stream>>>(x, offsets, ssrc, inv_deg, slotC, N);
    sage_linear2<<<(N * 128 + 255) / 256, 256, 0, stream>>>(slotC, x, Wl1, bl1, Wr1, h1_bf, N);

    // --- layer 2 + layer-3 products ---
    aggregate_bf128<<<(N * 16 + 255) / 256, 256, 0, stream>>>(h1_bf, offsets, ssrc,
                                                              inv_deg, aggB, N);
    gemm_l2_mfma<<<gemm_grid, 256, 0, stream>>>(aggB, h1_bf, Wt, bl2, W3c, g3b, slotA, N);

    // --- layer 3 finish + layer-4 products (fused gather+combine) ---
    aggregate_combine32<<<comb_grid, 256, 0, stream>>>(g3b, offsets, ssrc, inv_deg,
                                                       slotA, bl3, W4c, g4b, slotC, N);

    // --- layer 4 finish + layer-5 products ---
    aggregate_combine32<<<comb_grid, 256, 0, stream>>>(g4b, offsets, ssrc, inv_deg,
                                                       slotC, bl4, W5c, g5b, slotA, N);

    // --- layer 5 finish + output projection ---
    aggregate_final32<<<(N * 4 + 255) / 256, 256, 0, stream>>>(g5b, offsets, ssrc, inv_deg,
                                                               slotA, bl5, W_out, b_out,
                                                               out, N);
}